// Round 1
// baseline (743.296 us; speedup 1.0000x reference)
//
#include <hip/hip_runtime.h>
#include <cstdint>
#include <cmath>

#define DIMM 1024
#define NHEAD 16
#define HEADD 64
#define CHUNKC 128
#define NBATCH 4
#define TLEN 4096
#define NCHUNK 32
#define BT (NBATCH * TLEN)      // 16384
#define NSTACK (5 * DIMM)       // 5120

typedef unsigned short ushort_t;
typedef __attribute__((ext_vector_type(8))) short short8;
typedef __attribute__((ext_vector_type(4))) float f32x4;

__device__ __forceinline__ float blo(unsigned int u) { return __uint_as_float(u << 16); }
__device__ __forceinline__ float bhi(unsigned int u) { return __uint_as_float(u & 0xffff0000u); }
__device__ __forceinline__ ushort_t f2bf(float f) {
  unsigned int u = __float_as_uint(f);
  u += 0x7fffu + ((u >> 16) & 1u);
  return (ushort_t)(u >> 16);
}
__device__ __forceinline__ float bf2f(ushort_t s) { return __uint_as_float(((unsigned int)s) << 16); }
__device__ __forceinline__ unsigned pack2(float a, float b) {
  return (unsigned)f2bf(a) | ((unsigned)f2bf(b) << 16);
}

__device__ __forceinline__ void async16(const ushort_t* g, ushort_t* l) {
  __builtin_amdgcn_global_load_lds((__attribute__((address_space(1))) void*)g,
                                   (__attribute__((address_space(3))) void*)l, 16, 0, 0);
}

// ---------------------------------------------------------------------------
// Kernel 1: cast x -> bf16, pack 5 weights -> stacked bf16 [5120][1024],
//           pack 5 biases -> fp32 [5120]
// ---------------------------------------------------------------------------
__global__ __launch_bounds__(256) void k_cast(
    const float* __restrict__ x,
    const float* __restrict__ Wq, const float* __restrict__ Wk,
    const float* __restrict__ Wv, const float* __restrict__ Wb, const float* __restrict__ Wa,
    const float* __restrict__ bq, const float* __restrict__ bk,
    const float* __restrict__ bv, const float* __restrict__ bb, const float* __restrict__ ba,
    ushort_t* __restrict__ xb, ushort_t* __restrict__ wbm, float* __restrict__ bias_st) {
  const long XU = (long)BT * DIMM / 4;       // 4194304 float4 units
  const long WU = (long)NSTACK * DIMM / 4;   // 1310720
  const long BU = NSTACK / 4;                // 1280
  const long NU = XU + WU + BU;
  for (long u = (long)blockIdx.x * blockDim.x + threadIdx.x; u < NU;
       u += (long)gridDim.x * blockDim.x) {
    if (u < XU) {
      float4 f = ((const float4*)x)[u];
      ushort4 o;
      o.x = f2bf(f.x); o.y = f2bf(f.y); o.z = f2bf(f.z); o.w = f2bf(f.w);
      ((ushort4*)xb)[u] = o;
    } else if (u < XU + WU) {
      long j = u - XU;
      long e = j * 4;
      int row = (int)(e >> 10);
      int col = (int)(e & 1023);
      int p = row >> 10, wr = row & 1023;
      const float* Wp = (p == 0) ? Wq : (p == 1) ? Wk : (p == 2) ? Wv : (p == 3) ? Wb : Wa;
      float4 f = *(const float4*)(Wp + (size_t)wr * DIMM + col);
      ushort4 o;
      o.x = f2bf(f.x); o.y = f2bf(f.y); o.z = f2bf(f.z); o.w = f2bf(f.w);
      ((ushort4*)wbm)[j] = o;
    } else {
      long j = u - XU - WU;
      int e = (int)(j * 4);
      int p = e >> 10, r = e & 1023;
      const float* bp = (p == 0) ? bq : (p == 1) ? bk : (p == 2) ? bv : (p == 3) ? bb : ba;
      ((float4*)bias_st)[j] = *(const float4*)(bp + r);
    }
  }
}

// ---------------------------------------------------------------------------
// Kernel 2: fused projection GEMM, 256x256-tile 8-phase schedule (m201-style).
// out[m][n] = sum_k x[m][k]*Wst[n][k] + bias.  M=16384, N=5120, K=1024.
// 512 threads = 8 waves (2 M x 4 N); per-wave C = 4 disjoint 64x32 patches
// (one per block-quadrant).  BK=64, 16 K-tiles.
// LDS = 2 buffers x {A,B} x 2 halves x [128 rows][64 k] bf16 = 128 KiB.
// Swizzle: 16B slot s at row r holds logical k-slot s^(r&7); applied on the
// global source of global_load_lds (linear LDS dest) and on ds_read.
// Per phase: {ds_read subtile | stage 1 half-tile -> barrier -> setprio(1)
// 16 MFMA setprio(0) -> barrier}.  vmcnt(4) once per K-tile (counted, not 0):
// 2 half-tiles (4 loads/thread) stay in flight across barriers.
// Quadrant order alternates per tile parity ((0,0),(0,1),(1,0),(1,1) /
// (1,1),(1,0),(0,1),(0,0)) so each half's last ds_read completes >=1 phase
// before its LDS slot is restaged (clobber-safe; stage targets verified
// against last-read phases).  K accumulation order identical to the previous
// kernel -> bit-identical numerics.
// ---------------------------------------------------------------------------
#define REGN(bb,op,hh) ((((bb)*2+(op))*2+(hh))*16384)

#define STAGE(bb,op,hh,kt) do {                                                   \
    const ushort_t* _g = ((op) ? wbm + (((size_t)(bn0 + (hh)*128 + srow)) << 10)  \
                               : xb  + (((size_t)(bm0 + (hh)*128 + srow)) << 10)) \
                          + (kt)*64 + sswz;                                       \
    char* _l = sm + REGN(bb,op,hh) + tid*16;                                      \
    async16(_g, (ushort_t*)_l);                                                   \
    async16(_g + (64 << 10), (ushort_t*)(_l + 8192));                             \
  } while(0)

#define LDA(bb,Qr) do {                                                           \
    const char* _b = sm + REGN(bb,0,Qr) + ((wm*64 + lr) << 7);                    \
    _Pragma("unroll") for (int _f = 0; _f < 4; ++_f) {                            \
      a_[_f][0] = *(const short8*)(_b + (_f<<11) + (((0|quad)^sx)<<4));           \
      a_[_f][1] = *(const short8*)(_b + (_f<<11) + (((4|quad)^sx)<<4));           \
    } } while(0)

#define LDB(bb,Qc) do {                                                           \
    const char* _b = sm + REGN(bb,1,Qc) + ((wn*32 + lr) << 7);                    \
    _Pragma("unroll") for (int _g = 0; _g < 2; ++_g) {                            \
      b_[Qc][_g][0] = *(const short8*)(_b + (_g<<11) + (((0|quad)^sx)<<4));       \
      b_[Qc][_g][1] = *(const short8*)(_b + (_g<<11) + (((4|quad)^sx)<<4));       \
    } } while(0)

#define MFMAQ(Qr,Qc) do {                                                         \
    __builtin_amdgcn_s_setprio(1);                                                \
    _Pragma("unroll") for (int _f = 0; _f < 4; ++_f)                              \
    _Pragma("unroll") for (int _g = 0; _g < 2; ++_g) {                            \
      acc[Qr][Qc][_f][_g] = __builtin_amdgcn_mfma_f32_16x16x32_bf16(              \
          a_[_f][0], b_[Qc][_g][0], acc[Qr][Qc][_f][_g], 0, 0, 0);                \
      acc[Qr][Qc][_f][_g] = __builtin_amdgcn_mfma_f32_16x16x32_bf16(              \
          a_[_f][1], b_[Qc][_g][1], acc[Qr][Qc][_f][_g], 0, 0, 0);                \
    }                                                                             \
    __builtin_amdgcn_s_setprio(0); } while(0)

#define BARR __builtin_amdgcn_s_barrier()
#define VMC(n) asm volatile("s_waitcnt vmcnt(" #n ")" ::: "memory")

__global__ __launch_bounds__(512, 2) void k_proj(
    const ushort_t* __restrict__ xb, const ushort_t* __restrict__ wbm,
    const float* __restrict__ bias_st,
    ushort_t* __restrict__ qo, ushort_t* __restrict__ ko,
    ushort_t* __restrict__ vo, ushort_t* __restrict__ bo,
    float* __restrict__ ao) {
  __shared__ __align__(16) char sm[131072];   // 128 KiB: [buf][A/B][half][128][64] bf16
  const int tid = threadIdx.x;
  const int lane = tid & 63;
  const int wv = tid >> 6;        // 0..7
  const int wm = wv >> 2;         // 0..1  (M split)
  const int wn = wv & 3;          // 0..3  (N split)
  const int quad = lane >> 4, lr = lane & 15;
  const int sx = lr & 7;          // ds_read swizzle key (row&7 == lr&7 here)

  // XCD-aware bijective block swizzle (1280 % 8 == 0)
  const int id = blockIdx.x;
  const int swz = (id & 7) * 160 + (id >> 3);
  const int by = swz / 20;
  const int bx = swz - by * 20;
  const int bm0 = by * 256, bn0 = bx * 256;

  // staging constants: row-in-64 = tid>>3, phys slot = tid&7,
  // logical k-slot = phys ^ (row&7)  -> element offset sswz
  const int srow = tid >> 3;
  const int sswz = ((tid & 7) ^ (srow & 7)) << 3;

  f32x4 zero = {0.f, 0.f, 0.f, 0.f};
  f32x4 acc[2][2][4][2];
#pragma unroll
  for (int i = 0; i < 2; ++i)
#pragma unroll
    for (int j = 0; j < 2; ++j)
#pragma unroll
      for (int f = 0; f < 4; ++f)
#pragma unroll
        for (int g = 0; g < 2; ++g) acc[i][j][f][g] = zero;

  short8 a_[4][2];        // A frags for current Qr
  short8 b_[2][2][2];     // B frags, both Qc cached per tile

  // ---- prologue: tiles 0 (buf0) and 1 (buf1) fully staged ----
  STAGE(0,0,0,0); STAGE(0,0,1,0); STAGE(0,1,0,0); STAGE(0,1,1,0);
  STAGE(1,0,0,1); STAGE(1,0,1,1); STAGE(1,1,0,1); STAGE(1,1,1,1);
  VMC(8);   // tile 0 (oldest 8 loads) landed; tile 1 still in flight
  BARR;

#pragma unroll 1
  for (int t2 = 0; t2 < 8; ++t2) {
    const int te = 2 * t2;
    const bool enA = (t2 > 0);   // even tile stages sigma=te+1 (t2=0 done in prologue)
    const bool enB = (t2 < 7);   // sigma=te+2 <= 15
    // ---- even K-tile te (buffer 0), quadrants (0,0)(0,1)(1,0)(1,1) ----
    LDA(0,0); LDB(0,0); if (enA) STAGE(1,1,0, te+1); BARR; MFMAQ(0,0); BARR;
    LDB(0,1);           if (enA) STAGE(1,0,0, te+1); BARR; MFMAQ(0,1); BARR;
    LDA(0,1);           if (enB) STAGE(0,0,0, te+2); BARR; MFMAQ(1,0); BARR;
                        if (enB) STAGE(0,1,0, te+2); BARR; MFMAQ(1,1);
    if (t2 == 7) { VMC(0); } else { VMC(4); }   // tile te+1 fully landed
    BARR;
    // ---- odd K-tile te+1 (buffer 1), quadrants (1,1)(1,0)(0,1)(0,0) ----
    const bool enC = (t2 < 7);
    LDA(1,1); LDB(1,1); if (enC) STAGE(0,1,1, te+2); BARR; MFMAQ(1,1); BARR;
    LDB(1,0);           if (enC) STAGE(0,0,1, te+2); BARR; MFMAQ(1,0); BARR;
    LDA(1,0);           if (enC) STAGE(1,0,1, te+3); BARR; MFMAQ(0,1); BARR;
                        if (enC) STAGE(1,1,1, te+3); BARR; MFMAQ(0,0);
    if (t2 < 7) { VMC(4); BARR; }               // tile te+2 fully landed
  }

  // ---- epilogue: bias + activation, scatter to outputs ----
  const int p_id = bn0 >> 10;     // projection id, block-uniform (256 | 1024)
  const int ncol0 = bn0 & 1023;
#pragma unroll
  for (int Qc = 0; Qc < 2; ++Qc)
#pragma unroll
    for (int g = 0; g < 2; ++g) {
      const int colg = Qc * 128 + wn * 32 + g * 16 + lr;
      const float bias = bias_st[bn0 + colg];
      const int nc = ncol0 + colg;
#pragma unroll
      for (int Qr = 0; Qr < 2; ++Qr)
#pragma unroll
        for (int f = 0; f < 4; ++f)
#pragma unroll
          for (int r = 0; r < 4; ++r) {
            const int rowl = Qr * 128 + wm * 64 + f * 16 + quad * 4 + r;
            const size_t o = (size_t)(bm0 + rowl) * DIMM + nc;
            float val = acc[Qr][Qc][f][g][r] + bias;
            if (p_id == 0) {
              qo[o] = f2bf(val * 0.125f);
            } else if (p_id == 1) {
              ko[o] = f2bf(val * 0.125f);
            } else if (p_id == 2) {
              vo[o] = f2bf(val);
            } else if (p_id == 3) {
              float sp = (val > 20.f) ? val : log1pf(expf(val));
              bo[o] = f2bf(sp);
            } else {
              float c = fminf(fmaxf(val, -10.f), 10.f);
              ao[o] = 1.f / (1.f + expf(-c));
            }
          }
    }
}

#undef REGN
#undef STAGE
#undef LDA
#undef LDB
#undef MFMAQ
#undef BARR
#undef VMC

// ---------------------------------------------------------------------------
// Kernel 3: per-(b,n,h) stats.
// ---------------------------------------------------------------------------
__global__ __launch_bounds__(128) void k_stats(
    const float* __restrict__ alpha, const ushort_t* __restrict__ betaw,
    float* __restrict__ mArr, float* __restrict__ bmean, float* __restrict__ asum) {
  const int bnh = blockIdx.x;
  const int h = bnh & 15, n = (bnh >> 4) & 31, b = bnh >> 9;
  const int c = threadIdx.x;
  const size_t bt = (size_t)b * TLEN + n * CHUNKC + c;

  const float4* ap = (const float4*)(alpha + bt * DIMM + h * HEADD);
  float ls = 0.f;
#pragma unroll
  for (int w = 0; w < 16; ++w) {
    float4 a = ap[w];
    ls += logf(a.x) + logf(a.y) + logf(a.z) + logf(a.w);
  }
  const uint4* bp = (const uint4*)(betaw + bt * DIMM + h * HEADD);
  float bs = 0.f;
#pragma unroll
  for (int w = 0; w < 8; ++w) {
    uint4 u = bp[w];
    bs += blo(u.x) + bhi(u.x) + blo(u.y) + bhi(u.y) + blo(u.z) + bhi(u.z) + blo(u.w) + bhi(u.w);
  }
  float la = ls * (1.f / 64.f);

  __shared__ float s[128];
  s[c] = la;
  __syncthreads();
  for (int off = 1; off < 128; off <<= 1) {
    float t = (c >= off) ? s[c - off] : 0.f;
    __syncthreads();
    s[c] += t;
    __syncthreads();
  }
  float m = s[c];
  const size_t o = (size_t)bnh * CHUNKC + c;
  mArr[o] = m;
  bmean[o] = bs * (1.f / 64.f);
  if (c == 127) asum[bnh] = expf(m);
}

// ---------------------------------------------------------------------------
// Kernel 4: delta[b,n,h,kd,vd] = sum_c k[c,kd]*v[c,vd]*bmean[c]
// ---------------------------------------------------------------------------
__global__ __launch_bounds__(256) void k_delta(
    const ushort_t* __restrict__ kw, const ushort_t* __restrict__ vw,
    const float* __restrict__ bmean, float* __restrict__ delta) {
  __shared__ ushort_t kc[8192];
  __shared__ ushort_t vc[8192];
  __shared__ float bm[128];
  const int bnh = blockIdx.x;
  const int h = bnh & 15, n = (bnh >> 4) & 31, b = bnh >> 9;
  const int tid = threadIdx.x;
  const size_t bt0 = (size_t)b * TLEN + n * CHUNKC;

#pragma unroll
  for (int it = 0; it < 4; ++it) {
    int u = tid + it * 256;
    int row = u >> 3, col = (u & 7) * 8;
    size_t go = (bt0 + row) * DIMM + h * HEADD + col;
    ((uint4*)kc)[u] = *(const uint4*)(kw + go);
    ((uint4*)vc)[u] = *(const uint4*)(vw + go);
  }
  if (tid < 128) bm[tid] = bmean[(size_t)bnh * CHUNKC + tid];
  __syncthreads();

  const int kd = tid >> 2, v0 = (tid & 3) * 16;
  float acc[16];
#pragma unroll
  for (int l = 0; l < 16; ++l) acc[l] = 0.f;

#pragma unroll 4
  for (int c = 0; c < 128; ++c) {
    float kb = bf2f(kc[c * 64 + kd]) * bm[c];
    const uint4* vr = (const uint4*)(vc + c * 64 + v0);
    uint4 u0 = vr[0], u1 = vr[1];
    acc[0] += kb * blo(u0.x);  acc[1] += kb * bhi(u0.x);
    acc[2] += kb * blo(u0.y);  acc[3] += kb * bhi(u0.y);
    acc[4] += kb * blo(u0.z);  acc[5] += kb * bhi(u0.z);
    acc[6] += kb * blo(u0.w);  acc[7] += kb * bhi(u0.w);
    acc[8] += kb * blo(u1.x);  acc[9] += kb * bhi(u1.x);
    acc[10] += kb * blo(u1.y); acc[11] += kb * bhi(u1.y);
    acc[12] += kb * blo(u1.z); acc[13] += kb * bhi(u1.z);
    acc[14] += kb * blo(u1.w); acc[15] += kb * bhi(u1.w);
  }
  float* dst = delta + (size_t)bnh * 4096 + kd * 64 + v0;
#pragma unroll
  for (int l4 = 0; l4 < 4; ++l4)
    ((float4*)dst)[l4] = make_float4(acc[l4 * 4], acc[l4 * 4 + 1], acc[l4 * 4 + 2], acc[l4 * 4 + 3]);
}

// ---------------------------------------------------------------------------
// Kernel 5: scan over chunks. 1024 blocks: (b,h,group of 256 state elems).
// E_{n+1} = E_n * asum_n + delta_n. Entry states -> Earr; final -> state_out.
// ---------------------------------------------------------------------------
__global__ __launch_bounds__(256) void k_scan(
    const float* __restrict__ delta, const float* __restrict__ asum,
    float* __restrict__ Earr, float* __restrict__ state_out) {
  const int bh = blockIdx.x >> 4;        // b*16+h
  const int g = blockIdx.x & 15;
  const int b = bh >> 4, h = bh & 15;
  const int elem = g * 256 + threadIdx.x;
  float e = 0.f;
  for (int n = 0; n < 32; ++n) {
    const size_t o = (((size_t)b * 32 + n) * 16 + h) * 4096 + elem;
    const float a = asum[((size_t)b * 32 + n) * 16 + h];
    Earr[o] = e;
    e = e * a + delta[o];
  }
  state_out[(size_t)bh * 4096 + elem] = e;
}

// ---------------------------------------------------------------------------
// Kernel 6 (MFMA rewrite): per (b,n,h) block, 256 threads = 4 waves.
// GEMM1: S = q k^T (128x128x64), decay+mask in C-layout, P staged per-wave
// in LDS (A-layout round trip). GEMM2: y = P_ext @ Vb_ext, K=192 where
// columns 128..191 carry the inter-chunk memory term: P[i][128+kd] =
// q[i][kd]*exp(m_i), Vb_ext[128+kd][vd] = E[kd][vd].
// q/k fragments are read directly from global (L1-served, 4-wave reuse).
// ---------------------------------------------------------------------------
__global__ __launch_bounds__(256) void k_y(
    const ushort_t* __restrict__ qw, const ushort_t* __restrict__ kw,
    const ushort_t* __restrict__ vw, const ushort_t* __restrict__ betaw,
    const float* __restrict__ mArr, const float* __restrict__ Earr,
    float* __restrict__ yout) {
  // VbT[vd][j'] : j' in [0,192): 0..127 = (v*beta)^T, 128..191 = E^T column kd
  __shared__ __align__(16) ushort_t vbt[64][200];   // 25600 B (stride 400B: 2-way max)
  __shared__ __align__(16) ushort_t pst[4][32][40]; // 10240 B per-wave P staging
  __shared__ float ms[128];                         // 512 B
  const int bnh = blockIdx.x;
  const int h = bnh & 15, n = (bnh >> 4) & 31, b = bnh >> 9;
  const int tid = threadIdx.x;
  const int lane = tid & 63;
  const int wv = tid >> 6;
  const int quad = lane >> 4, lr = lane & 15;
  const int i0 = wv * 32;
  const size_t bt0 = (size_t)b * TLEN + n * CHUNKC;
  const size_t hoff = (size_t)h * HEADD;

  // ---- Phase A: stage VbT (v*beta transposed) + E^T + m ----
#pragma unroll
  for (int it = 0; it < 4; ++it) {
    int u = tid + it * 256;          // 0..1023
    int j = u & 127, vd0 = (u >> 7) * 8;
    size_t go = (bt0 + j) * DIMM + hoff + vd0;
    uint4 vv = *(const uint4*)(vw + go);
    uint4 bb2 = *(const uint4*)(betaw + go);
    vbt[vd0 + 0][j] = f2bf(blo(vv.x) * blo(bb2.x));
    vbt[vd0 + 1][j] = f2bf(bhi(vv.x) * bhi(bb2.x));
    vbt[vd0 + 2][j] = f2bf(blo(vv.y) * blo(bb2.y));
    vbt[vd0 + 3][j] = f2bf(bhi(vv.y) * bhi(bb2.y));
    vbt[vd0 + 4][j] = f2bf(blo(vv.z) * blo(bb2.z));
    vbt[vd0 + 5][j] = f2bf(bhi(vv.z) * bhi(bb2.z));
    vbt[vd0 + 6][j] = f2bf(blo(vv.w) * blo(bb2.w));
    vbt[vd0 + 7][j] = f2bf(bhi(vv.w) * bhi(bb2.w));
  }
  const float4* Eg = (const float4*)(Earr + (size_t)bnh * 4096);
#pragma unroll
  for (int it = 0; it < 4; ++it) {
    int u = tid + it * 256;          // 0..1023 float4 units
    int kd = u >> 4, vd0 = (u & 15) * 4;
    float4 ev = Eg[u];
    vbt[vd0 + 0][128 + kd] = f2bf(ev.x);
    vbt[vd0 + 1][128 + kd] = f2bf(ev.y);
    vbt[vd0 + 2][128 + kd] = f2bf(ev.z);
    vbt[vd0 + 3][128 + kd] = f2bf(ev.w);
  }
  if (tid < 128) ms[tid] = mArr[(size_t)bnh * CHUNKC + tid];
  __syncthreads();

  // ---- per-lane q A-fragments (from global) + row decay consts ----
  short8 qa[2][2];
#pragma unroll
  for (int it = 0; it < 2; ++it) {
    const ushort_t* qg = qw + (bt0 + i0 + it * 16 + lr) * DIMM + hoff + quad * 8;
    qa[it][0] = *(const short8*)(qg);
    qa[it][1] = *(const short8*)(qg + 32);
  }
  float mi[2][4];
#pragma unroll
  for (int it = 0; it < 2; ++it)
#pragma unroll
    for (int r = 0; r < 4; ++r) mi[it][r] = ms[i0 + it * 16 + quad * 4 + r];

  f32x4 zero = {0.f, 0.f, 0.f, 0.f};
  f32x4 acc2[2][4];
#pragma unroll
  for (int it = 0; it < 2; ++it)
#pragma unroll
    for (int nt = 0; nt < 4; ++nt) acc2[it][nt] = zero;

  // ---- attention steps: 4 x (32 j-columns) ----
  for (int js = 0; js < 4; ++js) {
    const int j0 = js * 32;
#pragma unroll
    for (int jsub = 0; jsub < 2; ++jsub) {
      const int j0s = j0 + jsub * 16;
      const ushort_t* kg = kw + (bt0 + j0s + lr) * DIMM + hoff + quad * 8;
      short8 kb0 = *(const short8*)(kg);
      short8 kb1 = *(const short8*)(kg + 32);
      const float mj = ms[j0s + lr];
#pragma unroll
      for (int it = 0; it < 2; ++it) {
        f32x4 s = __builtin_amdgcn_mfma_f32_16x16x32_bf16(qa[it][0], kb0, zero, 0, 0, 0);
        s = __builtin_amdgcn_mfma_f32_16x16x32_bf16(qa[it][1], kb1, s, 0, 0, 0);
#pragma unroll
        for (int r = 0; r < 4; ++r) {
          const int ig = i0 + it * 16 + quad * 4 + r;
          const int jg = j0s + lr;
          float w = (jg > ig) ? 0.f : s[r] * __expf(mi[it][r] - mj);
          pst[wv][it * 16 + quad * 4 + r][jsub * 16 + lr] = f2bf(w);
        }
      }
    }
    // GEMM2 accumulate this 32-wide K slab (LDS ops in-order within wave)
#pragma unroll
    for (int it = 0; it < 2; ++it) {
      short8 pa = *(const short8*)&pst[wv][it * 16 + lr][quad * 8];
#pragma unroll
      for (int nt = 0; nt < 4; ++nt) {
        short8 vb = *(const short8*)&vbt[nt * 16 + lr][j0 + quad * 8];
        acc2[it][nt] = __builtin_amdgcn_mfma_f32_16x16x32_bf16(pa, vb, acc2[it][nt], 0, 0, 0);
      }
    }
  }

  // ---- memory-term steps: 2 x (32 kd-columns): P = q*exp(m_i), V = E ----
#pragma unroll
  for (int es = 0; es < 2; ++es) {
    const int kd0 = es * 32;
    {
      const int row = lane >> 1;
      const int col0 = (lane & 1) * 16;
      const float ex = __expf(ms[i0 + row]);
      const ushort_t* qg = qw + (bt0 + i0 + row) * DIMM + hoff + kd0 + col0;
      uint4 u0 = *(const uint4*)(qg);
      uint4 u1 = *(const uint4*)(qg + 8);
      uint4 w0, w1;
      w0.x = pack2(blo(u0.x) * ex, bhi(u0.x) * ex);
      w0.y = pack2(blo(u0.y) * ex, bhi(u0.y) * ex);
      w0.z = pack2(blo(u0.z) * ex, bhi(u0.z) * ex);
      w0.w = pack2(blo(u0.w) * ex, bhi(u0.w) * ex);
      w1.x = pack2(blo(u1.x) * ex, bhi(u1.x) * ex);
      w1.y = pack2(blo(u1.y) * ex, bhi(u1.y) * ex);
      w1.z = pack2(blo(u1.z) * ex, bhi(u1.z) * ex);
      w1.w = pack2(blo(u1.w) * ex, bhi(u1.w) * ex);
      *(uint4*)&pst[wv][row][col0] = w0;
      *(uint4*)&pst[wv][row][col0 + 8] = w1;
    }
#pragma unroll
    for (int it = 0; it < 2; ++it) {
      short8 pa = *(const short8*)&pst[wv][it * 16 + lr][quad * 8];
#pragma unroll
      for (int nt = 0; nt < 4; ++nt) {
        short8 vb = *(const short8*)&vbt[nt * 16 + lr][128 + kd0 + quad * 8];
        acc2[it][nt] = __builtin_amdgcn_mfma_f32_16x16x32_bf16(pa, vb, acc2[it][nt], 0, 0, 0);
      }
    }
  }

  // ---- epilogue: C-layout scatter to y (fp32) ----
#pragma unroll
  for (int it = 0; it < 2; ++it) {
#pragma unroll
    for (int nt = 0; nt < 4; ++nt) {
      f32x4 a = acc2[it][nt];
#pragma unroll
      for (int r = 0; r < 4; ++r) {
        const int ig = i0 + it * 16 + quad * 4 + r;
        yout[(bt0 + ig) * DIMM + hoff + nt * 16 + lr] = a[r];
      }
    }
  }
}

// ---------------------------------------------------------------------------
extern "C" void kernel_launch(void* const* d_in, const int* in_sizes, int n_in,
                              void* d_out, int out_size, void* d_ws, size_t ws_size,
                              hipStream_t stream) {
  const float* x  = (const float*)d_in[0];
  const float* Wq = (const float*)d_in[1];
  const float* bq = (const float*)d_in[2];
  const float* Wk = (const float*)d_in[3];
  const float* bk = (const float*)d_in[4];
  const float* Wv = (const float*)d_in[5];
  const float* bv = (const float*)d_in[6];
  const float* Wb = (const float*)d_in[7];
  const float* bb = (const float*)d_in[8];
  const float* Wa = (const float*)d_in[9];
  const float* ba = (const float*)d_in[10];

  char* ws = (char*)d_ws;
  ushort_t* xb   = (ushort_t*)(ws + 0);           // 33554432 B
  ushort_t* wbm  = (ushort_t*)(ws + 33554432);    // 10485760 B
  float* bias_st = (float*)(ws + 44040192);       // 20480 B
  ushort_t* qw   = (ushort_t*)(ws + 44060672);    // 33554432 B
  ushort_t* kw   = (ushort_t*)(ws + 77615104);    // 33554432 B
  ushort_t* vw   = (ushort_t*)(ws + 111169536);   // 33554432 B
  ushort_t* bw   = (ushort_t*)(ws + 144723968);   // 33554432 B
  float* mArr    = (float*)(ws + 178278400);      // 1048576 B
  float* bmean   = (float*)(ws + 179326976);      // 1048576 B
  float* asum    = (float*)(ws + 180375552);      // 8192 B
  float* delta   = (float*)(ws + 180383744);      // 33554432 B
  float* Earr    = (float*)(ws + 213938176);      // 33554432 B  (total 247492608)

  float* yout = (float*)d_out;
  float* state_out = yout + (size_t)BT * DIMM;                 // + 16777216
  float* aout = state_out + (size_t)NBATCH * NHEAD * 64 * 64;  // + 262144

  k_cast<<<dim3(4096), dim3(256), 0, stream>>>(x, Wq, Wk, Wv, Wb, Wa,
                                               bq, bk, bv, bb, ba, xb, wbm, bias_st);
  k_proj<<<dim3(1280), dim3(512), 0, stream>>>(xb, wbm, bias_st, qw, kw, vw, bw, aout);
  k_stats<<<dim3(2048), dim3(128), 0, stream>>>(aout, bw, mArr, bmean, asum);
  k_delta<<<dim3(2048), dim3(256), 0, stream>>>(kw, vw, bmean, delta);
  k_scan<<<dim3(1024), dim3(256), 0, stream>>>(delta, asum, Earr, state_out);
  k_y<<<dim3(2048), dim3(256), 0, stream>>>(qw, kw, vw, bw, mArr, Earr, yout);
}

// Round 2
// 736.634 us; speedup vs baseline: 1.0090x; 1.0090x over previous
//
#include <hip/hip_runtime.h>
#include <cstdint>
#include <cmath>

#define DIMM 1024
#define NHEAD 16
#define HEADD 64
#define CHUNKC 128
#define NBATCH 4
#define TLEN 4096
#define NCHUNK 32
#define BT (NBATCH * TLEN)      // 16384
#define NSTACK (5 * DIMM)       // 5120

typedef unsigned short ushort_t;
typedef __attribute__((ext_vector_type(8))) short short8;
typedef __attribute__((ext_vector_type(4))) float f32x4;

__device__ __forceinline__ float blo(unsigned int u) { return __uint_as_float(u << 16); }
__device__ __forceinline__ float bhi(unsigned int u) { return __uint_as_float(u & 0xffff0000u); }
__device__ __forceinline__ ushort_t f2bf(float f) {
  unsigned int u = __float_as_uint(f);
  u += 0x7fffu + ((u >> 16) & 1u);
  return (ushort_t)(u >> 16);
}
__device__ __forceinline__ float bf2f(ushort_t s) { return __uint_as_float(((unsigned int)s) << 16); }
__device__ __forceinline__ unsigned pack2(float a, float b) {
  return (unsigned)f2bf(a) | ((unsigned)f2bf(b) << 16);
}

// Compiler-invisible global->LDS stage: the LDS write is hidden from alias
// analysis so the K-loop's ds_reads don't get conservative vmcnt(0) drains.
// m0 = wave-uniform LDS byte base; HW adds lane*16.
__device__ __forceinline__ void stage16(unsigned lds_base, const ushort_t* g) {
  asm volatile("s_mov_b32 m0, %0\n\t"
               "global_load_lds_dwordx4 %1, off"
               :: "s"(lds_base), "v"((unsigned long long)(size_t)g)
               : "memory");
}

// ---------------------------------------------------------------------------
// Kernel 1: cast x -> bf16, pack 5 weights -> stacked bf16 [5120][1024],
//           pack 5 biases -> fp32 [5120]
// ---------------------------------------------------------------------------
__global__ __launch_bounds__(256) void k_cast(
    const float* __restrict__ x,
    const float* __restrict__ Wq, const float* __restrict__ Wk,
    const float* __restrict__ Wv, const float* __restrict__ Wb, const float* __restrict__ Wa,
    const float* __restrict__ bq, const float* __restrict__ bk,
    const float* __restrict__ bv, const float* __restrict__ bb, const float* __restrict__ ba,
    ushort_t* __restrict__ xb, ushort_t* __restrict__ wbm, float* __restrict__ bias_st) {
  const long XU = (long)BT * DIMM / 4;       // 4194304 float4 units
  const long WU = (long)NSTACK * DIMM / 4;   // 1310720
  const long BU = NSTACK / 4;                // 1280
  const long NU = XU + WU + BU;
  for (long u = (long)blockIdx.x * blockDim.x + threadIdx.x; u < NU;
       u += (long)gridDim.x * blockDim.x) {
    if (u < XU) {
      float4 f = ((const float4*)x)[u];
      ushort4 o;
      o.x = f2bf(f.x); o.y = f2bf(f.y); o.z = f2bf(f.z); o.w = f2bf(f.w);
      ((ushort4*)xb)[u] = o;
    } else if (u < XU + WU) {
      long j = u - XU;
      long e = j * 4;
      int row = (int)(e >> 10);
      int col = (int)(e & 1023);
      int p = row >> 10, wr = row & 1023;
      const float* Wp = (p == 0) ? Wq : (p == 1) ? Wk : (p == 2) ? Wv : (p == 3) ? Wb : Wa;
      float4 f = *(const float4*)(Wp + (size_t)wr * DIMM + col);
      ushort4 o;
      o.x = f2bf(f.x); o.y = f2bf(f.y); o.z = f2bf(f.z); o.w = f2bf(f.w);
      ((ushort4*)wbm)[j] = o;
    } else {
      long j = u - XU - WU;
      int e = (int)(j * 4);
      int p = e >> 10, r = e & 1023;
      const float* bp = (p == 0) ? bq : (p == 1) ? bk : (p == 2) ? bv : (p == 3) ? bb : ba;
      ((float4*)bias_st)[j] = *(const float4*)(bp + r);
    }
  }
}

// ---------------------------------------------------------------------------
// Kernel 2: fused projection GEMM, 256x256-tile 8-phase schedule (m201-style).
// Identical schedule/semantics to the round-1 version (which passed); the ONLY
// change is that staging now goes through inline-asm global_load_lds_dwordx4
// (stage16) so the compiler's alias analysis can't see LDS writes and no
// longer inserts vmcnt(0) before every phase's ds_reads.  Counted vmcnt
// (VMC 4/8/0) at tile boundaries is now the only global-load wait.
// ---------------------------------------------------------------------------
#define REGN(bb,op,hh) ((((bb)*2+(op))*2+(hh))*16384)

#define STAGE(bb,op,hh,kt) do {                                                   \
    const ushort_t* _g = ((op) ? wbm + (((size_t)(bn0 + (hh)*128 + srow)) << 10)  \
                               : xb  + (((size_t)(bm0 + (hh)*128 + srow)) << 10)) \
                          + (kt)*64 + sswz;                                       \
    unsigned _l0 = (unsigned)__builtin_amdgcn_readfirstlane(                      \
        (int)(unsigned)(size_t)((__attribute__((address_space(3))) char*)sm       \
                                + REGN(bb,op,hh) + wv * 1024));                   \
    stage16(_l0, _g);                                                             \
    stage16(_l0 + 8192, _g + (64 << 10));                                         \
  } while(0)

#define LDA(bb,Qr) do {                                                           \
    const char* _b = sm + REGN(bb,0,Qr) + ((wm*64 + lr) << 7);                    \
    _Pragma("unroll") for (int _f = 0; _f < 4; ++_f) {                            \
      a_[_f][0] = *(const short8*)(_b + (_f<<11) + (((0|quad)^sx)<<4));           \
      a_[_f][1] = *(const short8*)(_b + (_f<<11) + (((4|quad)^sx)<<4));           \
    } } while(0)

#define LDB(bb,Qc) do {                                                           \
    const char* _b = sm + REGN(bb,1,Qc) + ((wn*32 + lr) << 7);                    \
    _Pragma("unroll") for (int _g = 0; _g < 2; ++_g) {                            \
      b_[Qc][_g][0] = *(const short8*)(_b + (_g<<11) + (((0|quad)^sx)<<4));       \
      b_[Qc][_g][1] = *(const short8*)(_b + (_g<<11) + (((4|quad)^sx)<<4));       \
    } } while(0)

#define MFMAQ(Qr,Qc) do {                                                         \
    __builtin_amdgcn_s_setprio(1);                                                \
    _Pragma("unroll") for (int _f = 0; _f < 4; ++_f)                              \
    _Pragma("unroll") for (int _g = 0; _g < 2; ++_g) {                            \
      acc[Qr][Qc][_f][_g] = __builtin_amdgcn_mfma_f32_16x16x32_bf16(              \
          a_[_f][0], b_[Qc][_g][0], acc[Qr][Qc][_f][_g], 0, 0, 0);                \
      acc[Qr][Qc][_f][_g] = __builtin_amdgcn_mfma_f32_16x16x32_bf16(              \
          a_[_f][1], b_[Qc][_g][1], acc[Qr][Qc][_f][_g], 0, 0, 0);                \
    }                                                                             \
    __builtin_amdgcn_s_setprio(0); } while(0)

#define BARR __builtin_amdgcn_s_barrier()
#define VMC(n) asm volatile("s_waitcnt vmcnt(" #n ")" ::: "memory")

__global__ __launch_bounds__(512, 2) void k_proj(
    const ushort_t* __restrict__ xb, const ushort_t* __restrict__ wbm,
    const float* __restrict__ bias_st,
    ushort_t* __restrict__ qo, ushort_t* __restrict__ ko,
    ushort_t* __restrict__ vo, ushort_t* __restrict__ bo,
    float* __restrict__ ao) {
  __shared__ __align__(16) char sm[131072];   // 128 KiB: [buf][A/B][half][128][64] bf16
  const int tid = threadIdx.x;
  const int lane = tid & 63;
  const int wv = tid >> 6;        // 0..7
  const int wm = wv >> 2;         // 0..1  (M split)
  const int wn = wv & 3;          // 0..3  (N split)
  const int quad = lane >> 4, lr = lane & 15;
  const int sx = lr & 7;          // ds_read swizzle key (row&7 == lr&7 here)

  // XCD-aware bijective block swizzle (1280 % 8 == 0)
  const int id = blockIdx.x;
  const int swz = (id & 7) * 160 + (id >> 3);
  const int by = swz / 20;
  const int bx = swz - by * 20;
  const int bm0 = by * 256, bn0 = bx * 256;

  // staging constants: row-in-64 = tid>>3, phys slot = tid&7,
  // logical k-slot = phys ^ (row&7)  -> element offset sswz
  const int srow = tid >> 3;
  const int sswz = ((tid & 7) ^ (srow & 7)) << 3;

  f32x4 zero = {0.f, 0.f, 0.f, 0.f};
  f32x4 acc[2][2][4][2];
#pragma unroll
  for (int i = 0; i < 2; ++i)
#pragma unroll
    for (int j = 0; j < 2; ++j)
#pragma unroll
      for (int f = 0; f < 4; ++f)
#pragma unroll
        for (int g = 0; g < 2; ++g) acc[i][j][f][g] = zero;

  short8 a_[4][2];        // A frags for current Qr
  short8 b_[2][2][2];     // B frags, both Qc cached per tile

  // ---- prologue: tiles 0 (buf0) and 1 (buf1) fully staged ----
  STAGE(0,0,0,0); STAGE(0,0,1,0); STAGE(0,1,0,0); STAGE(0,1,1,0);
  STAGE(1,0,0,1); STAGE(1,0,1,1); STAGE(1,1,0,1); STAGE(1,1,1,1);
  VMC(8);   // tile 0 (oldest 8 loads) landed; tile 1 still in flight
  BARR;

#pragma unroll 1
  for (int t2 = 0; t2 < 8; ++t2) {
    const int te = 2 * t2;
    const bool enA = (t2 > 0);   // even tile stages sigma=te+1 (t2=0 done in prologue)
    const bool enB = (t2 < 7);   // sigma=te+2 <= 15
    // ---- even K-tile te (buffer 0), quadrants (0,0)(0,1)(1,0)(1,1) ----
    LDA(0,0); LDB(0,0); if (enA) STAGE(1,1,0, te+1); BARR; MFMAQ(0,0); BARR;
    LDB(0,1);           if (enA) STAGE(1,0,0, te+1); BARR; MFMAQ(0,1); BARR;
    LDA(0,1);           if (enB) STAGE(0,0,0, te+2); BARR; MFMAQ(1,0); BARR;
                        if (enB) STAGE(0,1,0, te+2); BARR; MFMAQ(1,1);
    if (t2 == 7) { VMC(0); } else { VMC(4); }   // tile te+1 fully landed
    BARR;
    // ---- odd K-tile te+1 (buffer 1), quadrants (1,1)(1,0)(0,1)(0,0) ----
    const bool enC = (t2 < 7);
    LDA(1,1); LDB(1,1); if (enC) STAGE(0,1,1, te+2); BARR; MFMAQ(1,1); BARR;
    LDB(1,0);           if (enC) STAGE(0,0,1, te+2); BARR; MFMAQ(1,0); BARR;
    LDA(1,0);           if (enC) STAGE(1,0,1, te+3); BARR; MFMAQ(0,1); BARR;
                        if (enC) STAGE(1,1,1, te+3); BARR; MFMAQ(0,0);
    if (t2 < 7) { VMC(4); BARR; }               // tile te+2 fully landed
  }

  // ---- epilogue: bias + activation, scatter to outputs ----
  const int p_id = bn0 >> 10;     // projection id, block-uniform (256 | 1024)
  const int ncol0 = bn0 & 1023;
#pragma unroll
  for (int Qc = 0; Qc < 2; ++Qc)
#pragma unroll
    for (int g = 0; g < 2; ++g) {
      const int colg = Qc * 128 + wn * 32 + g * 16 + lr;
      const float bias = bias_st[bn0 + colg];
      const int nc = ncol0 + colg;
#pragma unroll
      for (int Qr = 0; Qr < 2; ++Qr)
#pragma unroll
        for (int f = 0; f < 4; ++f)
#pragma unroll
          for (int r = 0; r < 4; ++r) {
            const int rowl = Qr * 128 + wm * 64 + f * 16 + quad * 4 + r;
            const size_t o = (size_t)(bm0 + rowl) * DIMM + nc;
            float val = acc[Qr][Qc][f][g][r] + bias;
            if (p_id == 0) {
              qo[o] = f2bf(val * 0.125f);
            } else if (p_id == 1) {
              ko[o] = f2bf(val * 0.125f);
            } else if (p_id == 2) {
              vo[o] = f2bf(val);
            } else if (p_id == 3) {
              float sp = (val > 20.f) ? val : log1pf(expf(val));
              bo[o] = f2bf(sp);
            } else {
              float c = fminf(fmaxf(val, -10.f), 10.f);
              ao[o] = 1.f / (1.f + expf(-c));
            }
          }
    }
}

#undef REGN
#undef STAGE
#undef LDA
#undef LDB
#undef MFMAQ
#undef BARR
#undef VMC

// ---------------------------------------------------------------------------
// Kernel 3: per-(b,n,h) stats.
// ---------------------------------------------------------------------------
__global__ __launch_bounds__(128) void k_stats(
    const float* __restrict__ alpha, const ushort_t* __restrict__ betaw,
    float* __restrict__ mArr, float* __restrict__ bmean, float* __restrict__ asum) {
  const int bnh = blockIdx.x;
  const int h = bnh & 15, n = (bnh >> 4) & 31, b = bnh >> 9;
  const int c = threadIdx.x;
  const size_t bt = (size_t)b * TLEN + n * CHUNKC + c;

  const float4* ap = (const float4*)(alpha + bt * DIMM + h * HEADD);
  float ls = 0.f;
#pragma unroll
  for (int w = 0; w < 16; ++w) {
    float4 a = ap[w];
    ls += logf(a.x) + logf(a.y) + logf(a.z) + logf(a.w);
  }
  const uint4* bp = (const uint4*)(betaw + bt * DIMM + h * HEADD);
  float bs = 0.f;
#pragma unroll
  for (int w = 0; w < 8; ++w) {
    uint4 u = bp[w];
    bs += blo(u.x) + bhi(u.x) + blo(u.y) + bhi(u.y) + blo(u.z) + bhi(u.z) + blo(u.w) + bhi(u.w);
  }
  float la = ls * (1.f / 64.f);

  __shared__ float s[128];
  s[c] = la;
  __syncthreads();
  for (int off = 1; off < 128; off <<= 1) {
    float t = (c >= off) ? s[c - off] : 0.f;
    __syncthreads();
    s[c] += t;
    __syncthreads();
  }
  float m = s[c];
  const size_t o = (size_t)bnh * CHUNKC + c;
  mArr[o] = m;
  bmean[o] = bs * (1.f / 64.f);
  if (c == 127) asum[bnh] = expf(m);
}

// ---------------------------------------------------------------------------
// Kernel 4: delta[b,n,h,kd,vd] = sum_c k[c,kd]*v[c,vd]*bmean[c]
// ---------------------------------------------------------------------------
__global__ __launch_bounds__(256) void k_delta(
    const ushort_t* __restrict__ kw, const ushort_t* __restrict__ vw,
    const float* __restrict__ bmean, float* __restrict__ delta) {
  __shared__ ushort_t kc[8192];
  __shared__ ushort_t vc[8192];
  __shared__ float bm[128];
  const int bnh = blockIdx.x;
  const int h = bnh & 15, n = (bnh >> 4) & 31, b = bnh >> 9;
  const int tid = threadIdx.x;
  const size_t bt0 = (size_t)b * TLEN + n * CHUNKC;

#pragma unroll
  for (int it = 0; it < 4; ++it) {
    int u = tid + it * 256;
    int row = u >> 3, col = (u & 7) * 8;
    size_t go = (bt0 + row) * DIMM + h * HEADD + col;
    ((uint4*)kc)[u] = *(const uint4*)(kw + go);
    ((uint4*)vc)[u] = *(const uint4*)(vw + go);
  }
  if (tid < 128) bm[tid] = bmean[(size_t)bnh * CHUNKC + tid];
  __syncthreads();

  const int kd = tid >> 2, v0 = (tid & 3) * 16;
  float acc[16];
#pragma unroll
  for (int l = 0; l < 16; ++l) acc[l] = 0.f;

#pragma unroll 4
  for (int c = 0; c < 128; ++c) {
    float kb = bf2f(kc[c * 64 + kd]) * bm[c];
    const uint4* vr = (const uint4*)(vc + c * 64 + v0);
    uint4 u0 = vr[0], u1 = vr[1];
    acc[0] += kb * blo(u0.x);  acc[1] += kb * bhi(u0.x);
    acc[2] += kb * blo(u0.y);  acc[3] += kb * bhi(u0.y);
    acc[4] += kb * blo(u0.z);  acc[5] += kb * bhi(u0.z);
    acc[6] += kb * blo(u0.w);  acc[7] += kb * bhi(u0.w);
    acc[8] += kb * blo(u1.x);  acc[9] += kb * bhi(u1.x);
    acc[10] += kb * blo(u1.y); acc[11] += kb * bhi(u1.y);
    acc[12] += kb * blo(u1.z); acc[13] += kb * bhi(u1.z);
    acc[14] += kb * blo(u1.w); acc[15] += kb * bhi(u1.w);
  }
  float* dst = delta + (size_t)bnh * 4096 + kd * 64 + v0;
#pragma unroll
  for (int l4 = 0; l4 < 4; ++l4)
    ((float4*)dst)[l4] = make_float4(acc[l4 * 4], acc[l4 * 4 + 1], acc[l4 * 4 + 2], acc[l4 * 4 + 3]);
}

// ---------------------------------------------------------------------------
// Kernel 5: scan over chunks. 1024 blocks: (b,h,group of 256 state elems).
// E_{n+1} = E_n * asum_n + delta_n. Entry states -> Earr; final -> state_out.
// ---------------------------------------------------------------------------
__global__ __launch_bounds__(256) void k_scan(
    const float* __restrict__ delta, const float* __restrict__ asum,
    float* __restrict__ Earr, float* __restrict__ state_out) {
  const int bh = blockIdx.x >> 4;        // b*16+h
  const int g = blockIdx.x & 15;
  const int b = bh >> 4, h = bh & 15;
  const int elem = g * 256 + threadIdx.x;
  float e = 0.f;
  for (int n = 0; n < 32; ++n) {
    const size_t o = (((size_t)b * 32 + n) * 16 + h) * 4096 + elem;
    const float a = asum[((size_t)b * 32 + n) * 16 + h];
    Earr[o] = e;
    e = e * a + delta[o];
  }
  state_out[(size_t)bh * 4096 + elem] = e;
}

// ---------------------------------------------------------------------------
// Kernel 6 (MFMA rewrite): per (b,n,h) block, 256 threads = 4 waves.
// GEMM1: S = q k^T (128x128x64), decay+mask in C-layout, P staged per-wave
// in LDS (A-layout round trip). GEMM2: y = P_ext @ Vb_ext, K=192 where
// columns 128..191 carry the inter-chunk memory term: P[i][128+kd] =
// q[i][kd]*exp(m_i), Vb_ext[128+kd][vd] = E[kd][vd].
// q/k fragments are read directly from global (L1-served, 4-wave reuse).
// ---------------------------------------------------------------------------
__global__ __launch_bounds__(256) void k_y(
    const ushort_t* __restrict__ qw, const ushort_t* __restrict__ kw,
    const ushort_t* __restrict__ vw, const ushort_t* __restrict__ betaw,
    const float* __restrict__ mArr, const float* __restrict__ Earr,
    float* __restrict__ yout) {
  // VbT[vd][j'] : j' in [0,192): 0..127 = (v*beta)^T, 128..191 = E^T column kd
  __shared__ __align__(16) ushort_t vbt[64][200];   // 25600 B (stride 400B: 2-way max)
  __shared__ __align__(16) ushort_t pst[4][32][40]; // 10240 B per-wave P staging
  __shared__ float ms[128];                         // 512 B
  const int bnh = blockIdx.x;
  const int h = bnh & 15, n = (bnh >> 4) & 31, b = bnh >> 9;
  const int tid = threadIdx.x;
  const int lane = tid & 63;
  const int wv = tid >> 6;
  const int quad = lane >> 4, lr = lane & 15;
  const int i0 = wv * 32;
  const size_t bt0 = (size_t)b * TLEN + n * CHUNKC;
  const size_t hoff = (size_t)h * HEADD;

  // ---- Phase A: stage VbT (v*beta transposed) + E^T + m ----
#pragma unroll
  for (int it = 0; it < 4; ++it) {
    int u = tid + it * 256;          // 0..1023
    int j = u & 127, vd0 = (u >> 7) * 8;
    size_t go = (bt0 + j) * DIMM + hoff + vd0;
    uint4 vv = *(const uint4*)(vw + go);
    uint4 bb2 = *(const uint4*)(betaw + go);
    vbt[vd0 + 0][j] = f2bf(blo(vv.x) * blo(bb2.x));
    vbt[vd0 + 1][j] = f2bf(bhi(vv.x) * bhi(bb2.x));
    vbt[vd0 + 2][j] = f2bf(blo(vv.y) * blo(bb2.y));
    vbt[vd0 + 3][j] = f2bf(bhi(vv.y) * bhi(bb2.y));
    vbt[vd0 + 4][j] = f2bf(blo(vv.z) * blo(bb2.z));
    vbt[vd0 + 5][j] = f2bf(bhi(vv.z) * bhi(bb2.z));
    vbt[vd0 + 6][j] = f2bf(blo(vv.w) * blo(bb2.w));
    vbt[vd0 + 7][j] = f2bf(bhi(vv.w) * bhi(bb2.w));
  }
  const float4* Eg = (const float4*)(Earr + (size_t)bnh * 4096);
#pragma unroll
  for (int it = 0; it < 4; ++it) {
    int u = tid + it * 256;          // 0..1023 float4 units
    int kd = u >> 4, vd0 = (u & 15) * 4;
    float4 ev = Eg[u];
    vbt[vd0 + 0][128 + kd] = f2bf(ev.x);
    vbt[vd0 + 1][128 + kd] = f2bf(ev.y);
    vbt[vd0 + 2][128 + kd] = f2bf(ev.z);
    vbt[vd0 + 3][128 + kd] = f2bf(ev.w);
  }
  if (tid < 128) ms[tid] = mArr[(size_t)bnh * CHUNKC + tid];
  __syncthreads();

  // ---- per-lane q A-fragments (from global) + row decay consts ----
  short8 qa[2][2];
#pragma unroll
  for (int it = 0; it < 2; ++it) {
    const ushort_t* qg = qw + (bt0 + i0 + it * 16 + lr) * DIMM + hoff + quad * 8;
    qa[it][0] = *(const short8*)(qg);
    qa[it][1] = *(const short8*)(qg + 32);
  }
  float mi[2][4];
#pragma unroll
  for (int it = 0; it < 2; ++it)
#pragma unroll
    for (int r = 0; r < 4; ++r) mi[it][r] = ms[i0 + it * 16 + quad * 4 + r];

  f32x4 zero = {0.f, 0.f, 0.f, 0.f};
  f32x4 acc2[2][4];
#pragma unroll
  for (int it = 0; it < 2; ++it)
#pragma unroll
    for (int nt = 0; nt < 4; ++nt) acc2[it][nt] = zero;

  // ---- attention steps: 4 x (32 j-columns) ----
  for (int js = 0; js < 4; ++js) {
    const int j0 = js * 32;
#pragma unroll
    for (int jsub = 0; jsub < 2; ++jsub) {
      const int j0s = j0 + jsub * 16;
      const ushort_t* kg = kw + (bt0 + j0s + lr) * DIMM + hoff + quad * 8;
      short8 kb0 = *(const short8*)(kg);
      short8 kb1 = *(const short8*)(kg + 32);
      const float mj = ms[j0s + lr];
#pragma unroll
      for (int it = 0; it < 2; ++it) {
        f32x4 s = __builtin_amdgcn_mfma_f32_16x16x32_bf16(qa[it][0], kb0, zero, 0, 0, 0);
        s = __builtin_amdgcn_mfma_f32_16x16x32_bf16(qa[it][1], kb1, s, 0, 0, 0);
#pragma unroll
        for (int r = 0; r < 4; ++r) {
          const int ig = i0 + it * 16 + quad * 4 + r;
          const int jg = j0s + lr;
          float w = (jg > ig) ? 0.f : s[r] * __expf(mi[it][r] - mj);
          pst[wv][it * 16 + quad * 4 + r][jsub * 16 + lr] = f2bf(w);
        }
      }
    }
    // GEMM2 accumulate this 32-wide K slab (LDS ops in-order within wave)
#pragma unroll
    for (int it = 0; it < 2; ++it) {
      short8 pa = *(const short8*)&pst[wv][it * 16 + lr][quad * 8];
#pragma unroll
      for (int nt = 0; nt < 4; ++nt) {
        short8 vb = *(const short8*)&vbt[nt * 16 + lr][j0 + quad * 8];
        acc2[it][nt] = __builtin_amdgcn_mfma_f32_16x16x32_bf16(pa, vb, acc2[it][nt], 0, 0, 0);
      }
    }
  }

  // ---- memory-term steps: 2 x (32 kd-columns): P = q*exp(m_i), V = E ----
#pragma unroll
  for (int es = 0; es < 2; ++es) {
    const int kd0 = es * 32;
    {
      const int row = lane >> 1;
      const int col0 = (lane & 1) * 16;
      const float ex = __expf(ms[i0 + row]);
      const ushort_t* qg = qw + (bt0 + i0 + row) * DIMM + hoff + kd0 + col0;
      uint4 u0 = *(const uint4*)(qg);
      uint4 u1 = *(const uint4*)(qg + 8);
      uint4 w0, w1;
      w0.x = pack2(blo(u0.x) * ex, bhi(u0.x) * ex);
      w0.y = pack2(blo(u0.y) * ex, bhi(u0.y) * ex);
      w0.z = pack2(blo(u0.z) * ex, bhi(u0.z) * ex);
      w0.w = pack2(blo(u0.w) * ex, bhi(u0.w) * ex);
      w1.x = pack2(blo(u1.x) * ex, bhi(u1.x) * ex);
      w1.y = pack2(blo(u1.y) * ex, bhi(u1.y) * ex);
      w1.z = pack2(blo(u1.z) * ex, bhi(u1.z) * ex);
      w1.w = pack2(blo(u1.w) * ex, bhi(u1.w) * ex);
      *(uint4*)&pst[wv][row][col0] = w0;
      *(uint4*)&pst[wv][row][col0 + 8] = w1;
    }
#pragma unroll
    for (int it = 0; it < 2; ++it) {
      short8 pa = *(const short8*)&pst[wv][it * 16 + lr][quad * 8];
#pragma unroll
      for (int nt = 0; nt < 4; ++nt) {
        short8 vb = *(const short8*)&vbt[nt * 16 + lr][128 + kd0 + quad * 8];
        acc2[it][nt] = __builtin_amdgcn_mfma_f32_16x16x32_bf16(pa, vb, acc2[it][nt], 0, 0, 0);
      }
    }
  }

  // ---- epilogue: C-layout scatter to y (fp32) ----
#pragma unroll
  for (int it = 0; it < 2; ++it) {
#pragma unroll
    for (int nt = 0; nt < 4; ++nt) {
      f32x4 a = acc2[it][nt];
#pragma unroll
      for (int r = 0; r < 4; ++r) {
        const int ig = i0 + it * 16 + quad * 4 + r;
        yout[(bt0 + ig) * DIMM + hoff + nt * 16 + lr] = a[r];
      }
    }
  }
}

// ---------------------------------------------------------------------------
extern "C" void kernel_launch(void* const* d_in, const int* in_sizes, int n_in,
                              void* d_out, int out_size, void* d_ws, size_t ws_size,
                              hipStream_t stream) {
  const float* x  = (const float*)d_in[0];
  const float* Wq = (const float*)d_in[1];
  const float* bq = (const float*)d_in[2];
  const float* Wk = (const float*)d_in[3];
  const float* bk = (const float*)d_in[4];
  const float* Wv = (const float*)d_in[5];
  const float* bv = (const float*)d_in[6];
  const float* Wb = (const float*)d_in[7];
  const float* bb = (const float*)d_in[8];
  const float* Wa = (const float*)d_in[9];
  const float* ba = (const float*)d_in[10];

  char* ws = (char*)d_ws;
  ushort_t* xb   = (ushort_t*)(ws + 0);           // 33554432 B
  ushort_t* wbm  = (ushort_t*)(ws + 33554432);    // 10485760 B
  float* bias_st = (float*)(ws + 44040192);       // 20480 B
  ushort_t* qw   = (ushort_t*)(ws + 44060672);    // 33554432 B
  ushort_t* kw   = (ushort_t*)(ws + 77615104);    // 33554432 B
  ushort_t* vw   = (ushort_t*)(ws + 111169536);   // 33554432 B
  ushort_t* bw   = (ushort_t*)(ws + 144723968);   // 33554432 B
  float* mArr    = (float*)(ws + 178278400);      // 1048576 B
  float* bmean   = (float*)(ws + 179326976);      // 1048576 B
  float* asum    = (float*)(ws + 180375552);      // 8192 B
  float* delta   = (float*)(ws + 180383744);      // 33554432 B
  float* Earr    = (float*)(ws + 213938176);      // 33554432 B  (total 247492608)

  float* yout = (float*)d_out;
  float* state_out = yout + (size_t)BT * DIMM;                 // + 16777216
  float* aout = state_out + (size_t)NBATCH * NHEAD * 64 * 64;  // + 262144

  k_cast<<<dim3(4096), dim3(256), 0, stream>>>(x, Wq, Wk, Wv, Wb, Wa,
                                               bq, bk, bv, bb, ba, xb, wbm, bias_st);
  k_proj<<<dim3(1280), dim3(512), 0, stream>>>(xb, wbm, bias_st, qw, kw, vw, bw, aout);
  k_stats<<<dim3(2048), dim3(128), 0, stream>>>(aout, bw, mArr, bmean, asum);
  k_delta<<<dim3(2048), dim3(256), 0, stream>>>(kw, vw, bmean, delta);
  k_scan<<<dim3(1024), dim3(256), 0, stream>>>(delta, asum, Earr, state_out);
  k_y<<<dim3(2048), dim3(256), 0, stream>>>(qw, kw, vw, bw, mArr, Earr, yout);
}

// Round 3
// 677.574 us; speedup vs baseline: 1.0970x; 1.0872x over previous
//
#include <hip/hip_runtime.h>
#include <cstdint>
#include <cmath>

#define DIMM 1024
#define NHEAD 16
#define HEADD 64
#define CHUNKC 128
#define NBATCH 4
#define TLEN 4096
#define NCHUNK 32
#define BT (NBATCH * TLEN)      // 16384
#define NSTACK (5 * DIMM)       // 5120

typedef unsigned short ushort_t;
typedef __attribute__((ext_vector_type(8))) short short8;
typedef __attribute__((ext_vector_type(4))) float f32x4;

__device__ __forceinline__ float blo(unsigned int u) { return __uint_as_float(u << 16); }
__device__ __forceinline__ float bhi(unsigned int u) { return __uint_as_float(u & 0xffff0000u); }
__device__ __forceinline__ ushort_t f2bf(float f) {
  unsigned int u = __float_as_uint(f);
  u += 0x7fffu + ((u >> 16) & 1u);
  return (ushort_t)(u >> 16);
}
__device__ __forceinline__ float bf2f(ushort_t s) { return __uint_as_float(((unsigned int)s) << 16); }
__device__ __forceinline__ unsigned pack2(float a, float b) {
  return (unsigned)f2bf(a) | ((unsigned)f2bf(b) << 16);
}

__device__ __forceinline__ void async16(const ushort_t* g, ushort_t* l) {
  __builtin_amdgcn_global_load_lds((__attribute__((address_space(1))) void*)g,
                                   (__attribute__((address_space(3))) void*)l, 16, 0, 0);
}

// ---------------------------------------------------------------------------
// Kernel 1: cast x -> bf16, pack 5 weights -> stacked bf16 [5120][1024],
//           pack 5 biases -> fp32 [5120]
// ---------------------------------------------------------------------------
__global__ __launch_bounds__(256) void k_cast(
    const float* __restrict__ x,
    const float* __restrict__ Wq, const float* __restrict__ Wk,
    const float* __restrict__ Wv, const float* __restrict__ Wb, const float* __restrict__ Wa,
    const float* __restrict__ bq, const float* __restrict__ bk,
    const float* __restrict__ bv, const float* __restrict__ bb, const float* __restrict__ ba,
    ushort_t* __restrict__ xb, ushort_t* __restrict__ wbm, float* __restrict__ bias_st) {
  const long XU = (long)BT * DIMM / 4;       // 4194304 float4 units
  const long WU = (long)NSTACK * DIMM / 4;   // 1310720
  const long BU = NSTACK / 4;                // 1280
  const long NU = XU + WU + BU;
  for (long u = (long)blockIdx.x * blockDim.x + threadIdx.x; u < NU;
       u += (long)gridDim.x * blockDim.x) {
    if (u < XU) {
      float4 f = ((const float4*)x)[u];
      ushort4 o;
      o.x = f2bf(f.x); o.y = f2bf(f.y); o.z = f2bf(f.z); o.w = f2bf(f.w);
      ((ushort4*)xb)[u] = o;
    } else if (u < XU + WU) {
      long j = u - XU;
      long e = j * 4;
      int row = (int)(e >> 10);
      int col = (int)(e & 1023);
      int p = row >> 10, wr = row & 1023;
      const float* Wp = (p == 0) ? Wq : (p == 1) ? Wk : (p == 2) ? Wv : (p == 3) ? Wb : Wa;
      float4 f = *(const float4*)(Wp + (size_t)wr * DIMM + col);
      ushort4 o;
      o.x = f2bf(f.x); o.y = f2bf(f.y); o.z = f2bf(f.z); o.w = f2bf(f.w);
      ((ushort4*)wbm)[j] = o;
    } else {
      long j = u - XU - WU;
      int e = (int)(j * 4);
      int p = e >> 10, r = e & 1023;
      const float* bp = (p == 0) ? bq : (p == 1) ? bk : (p == 2) ? bv : (p == 3) ? bb : ba;
      ((float4*)bias_st)[j] = *(const float4*)(bp + r);
    }
  }
}

// ---------------------------------------------------------------------------
// Kernel 2: fused projection GEMM, round-0 proven structure + 3 surgical fixes:
//   * BK 32->64: half the barrier/vmcnt-drain events (m233: that drain is the
//     dominant 2-phase cost), same staged bytes.  LDS 32 KB -> still 4-5
//     blocks/CU so cross-block overlap (what made round-0 work) is preserved.
//   * both-sides XOR swizzle (verified 0-conflict in r1/r2): 16B slot s at
//     row r holds logical slot s^(r&7); applied on global src of
//     global_load_lds (linear LDS dest) and on the ds_read address.
//   * vectorized epilogue: acc -> LDS transpose (T[64][136]) -> dwordx4
//     stores (8 per thread instead of 64 scalar 2B stores; kills the
//     318MB->192MB write amplification).  fp32 alpha path keeps direct
//     stores (already full-sector).
//   * bijective XCD swizzle over the 5120-block grid (5120%8==0).
// M=16384, N=5120, K=1024, 128x128 tile, 256 thr = 4 waves, acc 4x4.
// Accumulation order over K unchanged -> bit-identical numerics.
// ---------------------------------------------------------------------------
__global__ __launch_bounds__(256) void k_proj(
    const ushort_t* __restrict__ xb, const ushort_t* __restrict__ wbm,
    const float* __restrict__ bias_st,
    ushort_t* __restrict__ qo, ushort_t* __restrict__ ko,
    ushort_t* __restrict__ vo, ushort_t* __restrict__ bo,
    float* __restrict__ ao) {
  __shared__ __align__(16) ushort_t smem[2 * 128 * 64];   // As | Bs, 32 KiB
  ushort_t* As = smem;
  ushort_t* Bs = smem + 128 * 64;
  const int tid = threadIdx.x;
  const int lane = tid & 63;
  const int wave = tid >> 6;
  const int quad = lane >> 4, lr = lane & 15;
  const int wr = (wave >> 1) * 64, wc = (wave & 1) * 64;
  const int sx = lr & 7;                 // ds_read swizzle key (row&7)

  // XCD-aware bijective swizzle: 5120 blocks, 640 contiguous per XCD
  const int lid = blockIdx.y * 40 + blockIdx.x;
  const int swz = (lid & 7) * 640 + (lid >> 3);
  const int byn = swz / 40;
  const int bxn = swz - byn * 40;
  const int bm0 = byn * 128, bn0 = bxn * 128;

  // staging: thread t loads 16B for row (t>>3) (+32 per chunk), phys slot
  // (t&7) carrying logical slot (t&7)^(row&7)
  const int trow = tid >> 3;
  const int gsw = ((tid & 7) ^ (trow & 7)) << 3;   // element col offset in 64
  const ushort_t* agb = xb + (size_t)(bm0 + trow) * DIMM + gsw;
  const ushort_t* bgb = wbm + (size_t)(bn0 + trow) * DIMM + gsw;

  f32x4 zero = {0.f, 0.f, 0.f, 0.f};
  f32x4 acc[4][4];
#pragma unroll
  for (int i = 0; i < 4; ++i)
#pragma unroll
    for (int j = 0; j < 4; ++j) acc[i][j] = zero;

  for (int kk = 0; kk < DIMM; kk += 64) {
    __syncthreads();
#pragma unroll
    for (int c = 0; c < 4; ++c) {
      async16(agb + (size_t)(c * 32) * DIMM + kk, As + c * 2048 + tid * 8);
      async16(bgb + (size_t)(c * 32) * DIMM + kk, Bs + c * 2048 + tid * 8);
    }
    __syncthreads();
#pragma unroll
    for (int kh = 0; kh < 2; ++kh) {
      short8 af[4], bfr[4];
#pragma unroll
      for (int i = 0; i < 4; ++i)
        af[i] = *(const short8*)(As + (wr + i * 16 + lr) * 64 + (((kh * 4 + quad) ^ sx) << 3));
#pragma unroll
      for (int j = 0; j < 4; ++j)
        bfr[j] = *(const short8*)(Bs + (wc + j * 16 + lr) * 64 + (((kh * 4 + quad) ^ sx) << 3));
#pragma unroll
      for (int i = 0; i < 4; ++i)
#pragma unroll
        for (int j = 0; j < 4; ++j)
          acc[i][j] = __builtin_amdgcn_mfma_f32_16x16x32_bf16(af[i], bfr[j], acc[i][j], 0, 0, 0);
    }
  }

  const int p_id = bn0 >> 10;          // projection id, block-uniform
  const int ncol0 = bn0 & 1023;

  if (p_id == 4) {
    // fp32 sigmoid path: scalar stores are full-sector (16 lanes x 4B = 64B)
#pragma unroll
    for (int j = 0; j < 4; ++j) {
      const int colg = wc + j * 16 + lr;
      const float bias = bias_st[bn0 + colg];
      const int nc = ncol0 + colg;
#pragma unroll
      for (int i = 0; i < 4; ++i)
#pragma unroll
        for (int r = 0; r < 4; ++r) {
          const int rowl = wr + i * 16 + quad * 4 + r;
          float val = acc[i][j][r] + bias;
          float c = fminf(fmaxf(val, -10.f), 10.f);
          ao[(size_t)(bm0 + rowl) * DIMM + nc] = 1.f / (1.f + expf(-c));
        }
    }
  } else {
    // bf16 paths: LDS transpose -> dwordx4 stores.
    ushort_t* outp = (p_id == 0) ? qo : (p_id == 1) ? ko : (p_id == 2) ? vo : bo;
    const float scl = (p_id <= 1) ? 0.125f : 1.f;
    ushort_t* T = smem;                 // [64][136] bf16 = 17 KiB (As+Bs dead)
    const int halfb = (wr == 64) ? 32 : 0;
#pragma unroll
    for (int pass = 0; pass < 2; ++pass) {
      __syncthreads();                  // T free (prev reads done)
#pragma unroll
      for (int ii = 0; ii < 2; ++ii) {
        const int i = pass * 2 + ii;
#pragma unroll
        for (int j = 0; j < 4; ++j) {
          const int col = wc + j * 16 + lr;
          const float bias = bias_st[bn0 + col];
#pragma unroll
          for (int r = 0; r < 4; ++r) {
            float val = acc[i][j][r] + bias;
            float ov;
            if (p_id == 3) ov = (val > 20.f) ? val : log1pf(expf(val));
            else ov = val * scl;
            T[(halfb + ii * 16 + quad * 4 + r) * 136 + col] = f2bf(ov);
          }
        }
      }
      __syncthreads();
      // 64 rows x 128 cols out: thread -> row tid>>2, 64B col chunk
      const int trw = tid >> 2;
      const int cch = (tid & 3) * 32;
      const int growl = pass * 32 + (trw & 31) + (trw >> 5) * 64;
      ushort_t* dst = outp + (size_t)(bm0 + growl) * DIMM + ncol0 + cch;
      const ushort_t* src = T + trw * 136 + cch;
#pragma unroll
      for (int u = 0; u < 4; ++u)
        *(uint4*)(dst + u * 8) = *(const uint4*)(src + u * 8);
    }
  }
}

// ---------------------------------------------------------------------------
// Kernel 3: per-(b,n,h) stats.
// ---------------------------------------------------------------------------
__global__ __launch_bounds__(128) void k_stats(
    const float* __restrict__ alpha, const ushort_t* __restrict__ betaw,
    float* __restrict__ mArr, float* __restrict__ bmean, float* __restrict__ asum) {
  const int bnh = blockIdx.x;
  const int h = bnh & 15, n = (bnh >> 4) & 31, b = bnh >> 9;
  const int c = threadIdx.x;
  const size_t bt = (size_t)b * TLEN + n * CHUNKC + c;

  const float4* ap = (const float4*)(alpha + bt * DIMM + h * HEADD);
  float ls = 0.f;
#pragma unroll
  for (int w = 0; w < 16; ++w) {
    float4 a = ap[w];
    ls += logf(a.x) + logf(a.y) + logf(a.z) + logf(a.w);
  }
  const uint4* bp = (const uint4*)(betaw + bt * DIMM + h * HEADD);
  float bs = 0.f;
#pragma unroll
  for (int w = 0; w < 8; ++w) {
    uint4 u = bp[w];
    bs += blo(u.x) + bhi(u.x) + blo(u.y) + bhi(u.y) + blo(u.z) + bhi(u.z) + blo(u.w) + bhi(u.w);
  }
  float la = ls * (1.f / 64.f);

  __shared__ float s[128];
  s[c] = la;
  __syncthreads();
  for (int off = 1; off < 128; off <<= 1) {
    float t = (c >= off) ? s[c - off] : 0.f;
    __syncthreads();
    s[c] += t;
    __syncthreads();
  }
  float m = s[c];
  const size_t o = (size_t)bnh * CHUNKC + c;
  mArr[o] = m;
  bmean[o] = bs * (1.f / 64.f);
  if (c == 127) asum[bnh] = expf(m);
}

// ---------------------------------------------------------------------------
// Kernel 4: delta[b,n,h,kd,vd] = sum_c k[c,kd]*v[c,vd]*bmean[c]
// ---------------------------------------------------------------------------
__global__ __launch_bounds__(256) void k_delta(
    const ushort_t* __restrict__ kw, const ushort_t* __restrict__ vw,
    const float* __restrict__ bmean, float* __restrict__ delta) {
  __shared__ ushort_t kc[8192];
  __shared__ ushort_t vc[8192];
  __shared__ float bm[128];
  const int bnh = blockIdx.x;
  const int h = bnh & 15, n = (bnh >> 4) & 31, b = bnh >> 9;
  const int tid = threadIdx.x;
  const size_t bt0 = (size_t)b * TLEN + n * CHUNKC;

#pragma unroll
  for (int it = 0; it < 4; ++it) {
    int u = tid + it * 256;
    int row = u >> 3, col = (u & 7) * 8;
    size_t go = (bt0 + row) * DIMM + h * HEADD + col;
    ((uint4*)kc)[u] = *(const uint4*)(kw + go);
    ((uint4*)vc)[u] = *(const uint4*)(vw + go);
  }
  if (tid < 128) bm[tid] = bmean[(size_t)bnh * CHUNKC + tid];
  __syncthreads();

  const int kd = tid >> 2, v0 = (tid & 3) * 16;
  float acc[16];
#pragma unroll
  for (int l = 0; l < 16; ++l) acc[l] = 0.f;

#pragma unroll 4
  for (int c = 0; c < 128; ++c) {
    float kb = bf2f(kc[c * 64 + kd]) * bm[c];
    const uint4* vr = (const uint4*)(vc + c * 64 + v0);
    uint4 u0 = vr[0], u1 = vr[1];
    acc[0] += kb * blo(u0.x);  acc[1] += kb * bhi(u0.x);
    acc[2] += kb * blo(u0.y);  acc[3] += kb * bhi(u0.y);
    acc[4] += kb * blo(u0.z);  acc[5] += kb * bhi(u0.z);
    acc[6] += kb * blo(u0.w);  acc[7] += kb * bhi(u0.w);
    acc[8] += kb * blo(u1.x);  acc[9] += kb * bhi(u1.x);
    acc[10] += kb * blo(u1.y); acc[11] += kb * bhi(u1.y);
    acc[12] += kb * blo(u1.z); acc[13] += kb * bhi(u1.z);
    acc[14] += kb * blo(u1.w); acc[15] += kb * bhi(u1.w);
  }
  float* dst = delta + (size_t)bnh * 4096 + kd * 64 + v0;
#pragma unroll
  for (int l4 = 0; l4 < 4; ++l4)
    ((float4*)dst)[l4] = make_float4(acc[l4 * 4], acc[l4 * 4 + 1], acc[l4 * 4 + 2], acc[l4 * 4 + 3]);
}

// ---------------------------------------------------------------------------
// Kernel 5: scan over chunks. 1024 blocks: (b,h,group of 256 state elems).
// E_{n+1} = E_n * asum_n + delta_n. Entry states -> Earr; final -> state_out.
// ---------------------------------------------------------------------------
__global__ __launch_bounds__(256) void k_scan(
    const float* __restrict__ delta, const float* __restrict__ asum,
    float* __restrict__ Earr, float* __restrict__ state_out) {
  const int bh = blockIdx.x >> 4;        // b*16+h
  const int g = blockIdx.x & 15;
  const int b = bh >> 4, h = bh & 15;
  const int elem = g * 256 + threadIdx.x;
  float e = 0.f;
  for (int n = 0; n < 32; ++n) {
    const size_t o = (((size_t)b * 32 + n) * 16 + h) * 4096 + elem;
    const float a = asum[((size_t)b * 32 + n) * 16 + h];
    Earr[o] = e;
    e = e * a + delta[o];
  }
  state_out[(size_t)bh * 4096 + elem] = e;
}

// ---------------------------------------------------------------------------
// Kernel 6 (MFMA rewrite): per (b,n,h) block, 256 threads = 4 waves.
// GEMM1: S = q k^T (128x128x64), decay+mask in C-layout, P staged per-wave
// in LDS (A-layout round trip). GEMM2: y = P_ext @ Vb_ext, K=192 where
// columns 128..191 carry the inter-chunk memory term: P[i][128+kd] =
// q[i][kd]*exp(m_i), Vb_ext[128+kd][vd] = E[kd][vd].
// q/k fragments are read directly from global (L1-served, 4-wave reuse).
// ---------------------------------------------------------------------------
__global__ __launch_bounds__(256) void k_y(
    const ushort_t* __restrict__ qw, const ushort_t* __restrict__ kw,
    const ushort_t* __restrict__ vw, const ushort_t* __restrict__ betaw,
    const float* __restrict__ mArr, const float* __restrict__ Earr,
    float* __restrict__ yout) {
  // VbT[vd][j'] : j' in [0,192): 0..127 = (v*beta)^T, 128..191 = E^T column kd
  __shared__ __align__(16) ushort_t vbt[64][200];   // 25600 B (stride 400B: 2-way max)
  __shared__ __align__(16) ushort_t pst[4][32][40]; // 10240 B per-wave P staging
  __shared__ float ms[128];                         // 512 B
  const int bnh = blockIdx.x;
  const int h = bnh & 15, n = (bnh >> 4) & 31, b = bnh >> 9;
  const int tid = threadIdx.x;
  const int lane = tid & 63;
  const int wv = tid >> 6;
  const int quad = lane >> 4, lr = lane & 15;
  const int i0 = wv * 32;
  const size_t bt0 = (size_t)b * TLEN + n * CHUNKC;
  const size_t hoff = (size_t)h * HEADD;

  // ---- Phase A: stage VbT (v*beta transposed) + E^T + m ----
#pragma unroll
  for (int it = 0; it < 4; ++it) {
    int u = tid + it * 256;          // 0..1023
    int j = u & 127, vd0 = (u >> 7) * 8;
    size_t go = (bt0 + j) * DIMM + hoff + vd0;
    uint4 vv = *(const uint4*)(vw + go);
    uint4 bb2 = *(const uint4*)(betaw + go);
    vbt[vd0 + 0][j] = f2bf(blo(vv.x) * blo(bb2.x));
    vbt[vd0 + 1][j] = f2bf(bhi(vv.x) * bhi(bb2.x));
    vbt[vd0 + 2][j] = f2bf(blo(vv.y) * blo(bb2.y));
    vbt[vd0 + 3][j] = f2bf(bhi(vv.y) * bhi(bb2.y));
    vbt[vd0 + 4][j] = f2bf(blo(vv.z) * blo(bb2.z));
    vbt[vd0 + 5][j] = f2bf(bhi(vv.z) * bhi(bb2.z));
    vbt[vd0 + 6][j] = f2bf(blo(vv.w) * blo(bb2.w));
    vbt[vd0 + 7][j] = f2bf(bhi(vv.w) * bhi(bb2.w));
  }
  const float4* Eg = (const float4*)(Earr + (size_t)bnh * 4096);
#pragma unroll
  for (int it = 0; it < 4; ++it) {
    int u = tid + it * 256;          // 0..1023 float4 units
    int kd = u >> 4, vd0 = (u & 15) * 4;
    float4 ev = Eg[u];
    vbt[vd0 + 0][128 + kd] = f2bf(ev.x);
    vbt[vd0 + 1][128 + kd] = f2bf(ev.y);
    vbt[vd0 + 2][128 + kd] = f2bf(ev.z);
    vbt[vd0 + 3][128 + kd] = f2bf(ev.w);
  }
  if (tid < 128) ms[tid] = mArr[(size_t)bnh * CHUNKC + tid];
  __syncthreads();

  // ---- per-lane q A-fragments (from global) + row decay consts ----
  short8 qa[2][2];
#pragma unroll
  for (int it = 0; it < 2; ++it) {
    const ushort_t* qg = qw + (bt0 + i0 + it * 16 + lr) * DIMM + hoff + quad * 8;
    qa[it][0] = *(const short8*)(qg);
    qa[it][1] = *(const short8*)(qg + 32);
  }
  float mi[2][4];
#pragma unroll
  for (int it = 0; it < 2; ++it)
#pragma unroll
    for (int r = 0; r < 4; ++r) mi[it][r] = ms[i0 + it * 16 + quad * 4 + r];

  f32x4 zero = {0.f, 0.f, 0.f, 0.f};
  f32x4 acc2[2][4];
#pragma unroll
  for (int it = 0; it < 2; ++it)
#pragma unroll
    for (int nt = 0; nt < 4; ++nt) acc2[it][nt] = zero;

  // ---- attention steps: 4 x (32 j-columns) ----
  for (int js = 0; js < 4; ++js) {
    const int j0 = js * 32;
#pragma unroll
    for (int jsub = 0; jsub < 2; ++jsub) {
      const int j0s = j0 + jsub * 16;
      const ushort_t* kg = kw + (bt0 + j0s + lr) * DIMM + hoff + quad * 8;
      short8 kb0 = *(const short8*)(kg);
      short8 kb1 = *(const short8*)(kg + 32);
      const float mj = ms[j0s + lr];
#pragma unroll
      for (int it = 0; it < 2; ++it) {
        f32x4 s = __builtin_amdgcn_mfma_f32_16x16x32_bf16(qa[it][0], kb0, zero, 0, 0, 0);
        s = __builtin_amdgcn_mfma_f32_16x16x32_bf16(qa[it][1], kb1, s, 0, 0, 0);
#pragma unroll
        for (int r = 0; r < 4; ++r) {
          const int ig = i0 + it * 16 + quad * 4 + r;
          const int jg = j0s + lr;
          float w = (jg > ig) ? 0.f : s[r] * __expf(mi[it][r] - mj);
          pst[wv][it * 16 + quad * 4 + r][jsub * 16 + lr] = f2bf(w);
        }
      }
    }
    // GEMM2 accumulate this 32-wide K slab (LDS ops in-order within wave)
#pragma unroll
    for (int it = 0; it < 2; ++it) {
      short8 pa = *(const short8*)&pst[wv][it * 16 + lr][quad * 8];
#pragma unroll
      for (int nt = 0; nt < 4; ++nt) {
        short8 vb = *(const short8*)&vbt[nt * 16 + lr][j0 + quad * 8];
        acc2[it][nt] = __builtin_amdgcn_mfma_f32_16x16x32_bf16(pa, vb, acc2[it][nt], 0, 0, 0);
      }
    }
  }

  // ---- memory-term steps: 2 x (32 kd-columns): P = q*exp(m_i), V = E ----
#pragma unroll
  for (int es = 0; es < 2; ++es) {
    const int kd0 = es * 32;
    {
      const int row = lane >> 1;
      const int col0 = (lane & 1) * 16;
      const float ex = __expf(ms[i0 + row]);
      const ushort_t* qg = qw + (bt0 + i0 + row) * DIMM + hoff + kd0 + col0;
      uint4 u0 = *(const uint4*)(qg);
      uint4 u1 = *(const uint4*)(qg + 8);
      uint4 w0, w1;
      w0.x = pack2(blo(u0.x) * ex, bhi(u0.x) * ex);
      w0.y = pack2(blo(u0.y) * ex, bhi(u0.y) * ex);
      w0.z = pack2(blo(u0.z) * ex, bhi(u0.z) * ex);
      w0.w = pack2(blo(u0.w) * ex, bhi(u0.w) * ex);
      w1.x = pack2(blo(u1.x) * ex, bhi(u1.x) * ex);
      w1.y = pack2(blo(u1.y) * ex, bhi(u1.y) * ex);
      w1.z = pack2(blo(u1.z) * ex, bhi(u1.z) * ex);
      w1.w = pack2(blo(u1.w) * ex, bhi(u1.w) * ex);
      *(uint4*)&pst[wv][row][col0] = w0;
      *(uint4*)&pst[wv][row][col0 + 8] = w1;
    }
#pragma unroll
    for (int it = 0; it < 2; ++it) {
      short8 pa = *(const short8*)&pst[wv][it * 16 + lr][quad * 8];
#pragma unroll
      for (int nt = 0; nt < 4; ++nt) {
        short8 vb = *(const short8*)&vbt[nt * 16 + lr][128 + kd0 + quad * 8];
        acc2[it][nt] = __builtin_amdgcn_mfma_f32_16x16x32_bf16(pa, vb, acc2[it][nt], 0, 0, 0);
      }
    }
  }

  // ---- epilogue: C-layout scatter to y (fp32) ----
#pragma unroll
  for (int it = 0; it < 2; ++it) {
#pragma unroll
    for (int nt = 0; nt < 4; ++nt) {
      f32x4 a = acc2[it][nt];
#pragma unroll
      for (int r = 0; r < 4; ++r) {
        const int ig = i0 + it * 16 + quad * 4 + r;
        yout[(bt0 + ig) * DIMM + hoff + nt * 16 + lr] = a[r];
      }
    }
  }
}

// ---------------------------------------------------------------------------
extern "C" void kernel_launch(void* const* d_in, const int* in_sizes, int n_in,
                              void* d_out, int out_size, void* d_ws, size_t ws_size,
                              hipStream_t stream) {
  const float* x  = (const float*)d_in[0];
  const float* Wq = (const float*)d_in[1];
  const float* bq = (const float*)d_in[2];
  const float* Wk = (const float*)d_in[3];
  const float* bk = (const float*)d_in[4];
  const float* Wv = (const float*)d_in[5];
  const float* bv = (const float*)d_in[6];
  const float* Wb = (const float*)d_in[7];
  const float* bb = (const float*)d_in[8];
  const float* Wa = (const float*)d_in[9];
  const float* ba = (const float*)d_in[10];

  char* ws = (char*)d_ws;
  ushort_t* xb   = (ushort_t*)(ws + 0);           // 33554432 B
  ushort_t* wbm  = (ushort_t*)(ws + 33554432);    // 10485760 B
  float* bias_st = (float*)(ws + 44040192);       // 20480 B
  ushort_t* qw   = (ushort_t*)(ws + 44060672);    // 33554432 B
  ushort_t* kw   = (ushort_t*)(ws + 77615104);    // 33554432 B
  ushort_t* vw   = (ushort_t*)(ws + 111169536);   // 33554432 B
  ushort_t* bw   = (ushort_t*)(ws + 144723968);   // 33554432 B
  float* mArr    = (float*)(ws + 178278400);      // 1048576 B
  float* bmean   = (float*)(ws + 179326976);      // 1048576 B
  float* asum    = (float*)(ws + 180375552);      // 8192 B
  float* delta   = (float*)(ws + 180383744);      // 33554432 B
  float* Earr    = (float*)(ws + 213938176);      // 33554432 B  (total 247492608)

  float* yout = (float*)d_out;
  float* state_out = yout + (size_t)BT * DIMM;                 // + 16777216
  float* aout = state_out + (size_t)NBATCH * NHEAD * 64 * 64;  // + 262144

  k_cast<<<dim3(4096), dim3(256), 0, stream>>>(x, Wq, Wk, Wv, Wb, Wa,
                                               bq, bk, bv, bb, ba, xb, wbm, bias_st);
  k_proj<<<dim3(40, 128), dim3(256), 0, stream>>>(xb, wbm, bias_st, qw, kw, vw, bw, aout);
  k_stats<<<dim3(2048), dim3(128), 0, stream>>>(aout, bw, mArr, bmean, asum);
  k_delta<<<dim3(2048), dim3(256), 0, stream>>>(kw, vw, bmean, delta);
  k_scan<<<dim3(1024), dim3(256), 0, stream>>>(delta, asum, Earr, state_out);
  k_y<<<dim3(2048), dim3(256), 0, stream>>>(qw, kw, vw, bw, mArr, Earr, yout);
}

// Round 4
// 618.804 us; speedup vs baseline: 1.2012x; 1.0950x over previous
//
#include <hip/hip_runtime.h>
#include <cstdint>
#include <cmath>

#define DIMM 1024
#define NHEAD 16
#define HEADD 64
#define CHUNKC 128
#define NBATCH 4
#define TLEN 4096
#define NCHUNK 32
#define BT (NBATCH * TLEN)      // 16384
#define NSTACK (5 * DIMM)       // 5120

typedef unsigned short ushort_t;
typedef __attribute__((ext_vector_type(8))) short short8;
typedef __attribute__((ext_vector_type(4))) float f32x4;

__device__ __forceinline__ float blo(unsigned int u) { return __uint_as_float(u << 16); }
__device__ __forceinline__ float bhi(unsigned int u) { return __uint_as_float(u & 0xffff0000u); }
__device__ __forceinline__ ushort_t f2bf(float f) {
  unsigned int u = __float_as_uint(f);
  u += 0x7fffu + ((u >> 16) & 1u);
  return (ushort_t)(u >> 16);
}
__device__ __forceinline__ float bf2f(ushort_t s) { return __uint_as_float(((unsigned int)s) << 16); }
__device__ __forceinline__ unsigned pack2(float a, float b) {
  return (unsigned)f2bf(a) | ((unsigned)f2bf(b) << 16);
}

// Compiler-invisible global->LDS stage (HW-verified in rounds 1/2): the LDS
// write is hidden from alias analysis so no auto vmcnt(0) is inserted between
// stage-issue and the K-loop's ds_reads.  m0 = wave-uniform LDS byte base;
// HW adds lane*16.
__device__ __forceinline__ void stage16(unsigned lds_base, const ushort_t* g) {
  asm volatile("s_mov_b32 m0, %0\n\t"
               "global_load_lds_dwordx4 %1, off"
               :: "s"(lds_base), "v"((unsigned long long)(size_t)g)
               : "memory");
}

// ---------------------------------------------------------------------------
// Kernel 1: cast x -> bf16, pack 5 weights -> stacked bf16 [5120][1024],
//           pack 5 biases -> fp32 [5120]
// ---------------------------------------------------------------------------
__global__ __launch_bounds__(256) void k_cast(
    const float* __restrict__ x,
    const float* __restrict__ Wq, const float* __restrict__ Wk,
    const float* __restrict__ Wv, const float* __restrict__ Wb, const float* __restrict__ Wa,
    const float* __restrict__ bq, const float* __restrict__ bk,
    const float* __restrict__ bv, const float* __restrict__ bb, const float* __restrict__ ba,
    ushort_t* __restrict__ xb, ushort_t* __restrict__ wbm, float* __restrict__ bias_st) {
  const long XU = (long)BT * DIMM / 4;       // 4194304 float4 units
  const long WU = (long)NSTACK * DIMM / 4;   // 1310720
  const long BU = NSTACK / 4;                // 1280
  const long NU = XU + WU + BU;
  for (long u = (long)blockIdx.x * blockDim.x + threadIdx.x; u < NU;
       u += (long)gridDim.x * blockDim.x) {
    if (u < XU) {
      float4 f = ((const float4*)x)[u];
      ushort4 o;
      o.x = f2bf(f.x); o.y = f2bf(f.y); o.z = f2bf(f.z); o.w = f2bf(f.w);
      ((ushort4*)xb)[u] = o;
    } else if (u < XU + WU) {
      long j = u - XU;
      long e = j * 4;
      int row = (int)(e >> 10);
      int col = (int)(e & 1023);
      int p = row >> 10, wr = row & 1023;
      const float* Wp = (p == 0) ? Wq : (p == 1) ? Wk : (p == 2) ? Wv : (p == 3) ? Wb : Wa;
      float4 f = *(const float4*)(Wp + (size_t)wr * DIMM + col);
      ushort4 o;
      o.x = f2bf(f.x); o.y = f2bf(f.y); o.z = f2bf(f.z); o.w = f2bf(f.w);
      ((ushort4*)wbm)[j] = o;
    } else {
      long j = u - XU - WU;
      int e = (int)(j * 4);
      int p = e >> 10, r = e & 1023;
      const float* bp = (p == 0) ? bq : (p == 1) ? bk : (p == 2) ? bv : (p == 3) ? bb : ba;
      ((float4*)bias_st)[j] = *(const float4*)(bp + r);
    }
  }
}

// ---------------------------------------------------------------------------
// Kernel 2: fused projection GEMM.  128x128 tile, BK=32, 4 waves, dbuf LDS.
// Round-4 changes vs round-3 (theory: exposed stage latency, not barrier count):
//   * natural blockIdx order restored (round-3 XCD swizzle quadrupled FETCH
//     646 vs 167 MB -> reverted).
//   * double-buffered 1-barrier K-loop: per iter {vmcnt(0)+s_barrier ->
//     issue stage(next) -> ds_read(cur)+16 MFMA}.  Stage issued BEFORE
//     compute, waited only at next iter's top -> latency hidden under MFMA
//     + 5 blocks/CU TLP (LDS 32 KB).  Staging via inline-asm stage16
//     (compiler-invisible, HW-verified r1/r2) so the counted vmcnt is the
//     only global wait; depth-1 dbuf => vmcnt(0) == "wait my 4 loads".
//   * 4-slot swizzle: phys 16B slot = logical ^ ((row>>1)&3) -> 2 lanes/bank
//     on ds_read_b128 (same structure as round-3's measured-0-conflict map).
//   * vectorized transpose epilogue kept (WRITE 318->198 MB verified).
// K accumulation order identical -> bit-identical numerics.
// ---------------------------------------------------------------------------
#define BARR __builtin_amdgcn_s_barrier()
#define VMC0 asm volatile("s_waitcnt vmcnt(0)" ::: "memory")

// LDS byte map: buf b in [0,2): base b*16384; A at +0, B at +8192;
// within a matrix: row r (0..127) at r*64, phys 16B-slot p at +p*16.
// Thread t stages rows {t>>2, 64+(t>>2)}, phys slot t&3, carrying logical
// slot (t&3)^((t>>3)&3).
#define STAGEP(bb, kt) do {                                                      \
    const size_t _ko = (size_t)(kt) * 32;                                        \
    unsigned _base = (unsigned)__builtin_amdgcn_readfirstlane(                   \
        (int)(unsigned)(size_t)((__attribute__((address_space(3))) char*)smem    \
                                + (bb) * 16384 + wv1024));                       \
    stage16(_base,         agb + _ko);                                           \
    stage16(_base + 4096,  agb + (size_t)64 * DIMM + _ko);                       \
    stage16(_base + 8192,  bgb + _ko);                                           \
    stage16(_base + 12288, bgb + (size_t)64 * DIMM + _ko);                       \
  } while (0)

__global__ __launch_bounds__(256) void k_proj(
    const ushort_t* __restrict__ xb, const ushort_t* __restrict__ wbm,
    const float* __restrict__ bias_st,
    ushort_t* __restrict__ qo, ushort_t* __restrict__ ko,
    ushort_t* __restrict__ vo, ushort_t* __restrict__ bo,
    float* __restrict__ ao) {
  __shared__ __align__(16) char smem[32768];   // 2 bufs x (A 8KB + B 8KB)
  const int tid = threadIdx.x;
  const int lane = tid & 63;
  const int wave = tid >> 6;
  const int quad = lane >> 4, lr = lane & 15;
  const int wr = (wave >> 1) * 64, wc = (wave & 1) * 64;
  const int sx = (lr >> 1) & 3;          // ds_read swizzle key ((row>>1)&3)
  const int wv1024 = wave * 1024;        // wave's slice of a 4KB chunk

  const int bm0 = blockIdx.y * 128, bn0 = blockIdx.x * 128;

  // staging source: thread t -> row t>>2 (+64 for chunk 1), logical col
  // slot (t&3)^((t>>3)&3)  [key (row>>1)&3 is identical for both chunks]
  const int trow = tid >> 2;
  const int gcol = (((tid & 3) ^ ((tid >> 3) & 3)) << 3);
  const ushort_t* agb = xb + (size_t)(bm0 + trow) * DIMM + gcol;
  const ushort_t* bgb = wbm + (size_t)(bn0 + trow) * DIMM + gcol;

  f32x4 zero = {0.f, 0.f, 0.f, 0.f};
  f32x4 acc[4][4];
#pragma unroll
  for (int i = 0; i < 4; ++i)
#pragma unroll
    for (int j = 0; j < 4; ++j) acc[i][j] = zero;

  STAGEP(0, 0);                          // prologue: tile 0 in flight

#pragma unroll 2
  for (int kk = 0; kk < 32; ++kk) {
    VMC0;                                // my 4 loads (buffer kk&1) landed
    BARR;                                // everyone's landed; prev reads done
    if (kk < 31) STAGEP((kk + 1) & 1, kk + 1);   // overlap next stage w/ MFMA
    const char* Ab = smem + (kk & 1) * 16384;
    const char* Bb = Ab + 8192;
    short8 af[4], bfr[4];
#pragma unroll
    for (int i = 0; i < 4; ++i)
      af[i] = *(const short8*)(Ab + (wr + i * 16 + lr) * 64 + ((quad ^ sx) << 4));
#pragma unroll
    for (int j = 0; j < 4; ++j)
      bfr[j] = *(const short8*)(Bb + (wc + j * 16 + lr) * 64 + ((quad ^ sx) << 4));
#pragma unroll
    for (int i = 0; i < 4; ++i)
#pragma unroll
      for (int j = 0; j < 4; ++j)
        acc[i][j] = __builtin_amdgcn_mfma_f32_16x16x32_bf16(af[i], bfr[j], acc[i][j], 0, 0, 0);
  }

  const int p_id = bn0 >> 10;          // projection id, block-uniform
  const int ncol0 = bn0 & 1023;

  if (p_id == 4) {
    // fp32 sigmoid path: scalar stores are full-sector (16 lanes x 4B = 64B)
#pragma unroll
    for (int j = 0; j < 4; ++j) {
      const int colg = wc + j * 16 + lr;
      const float bias = bias_st[bn0 + colg];
      const int nc = ncol0 + colg;
#pragma unroll
      for (int i = 0; i < 4; ++i)
#pragma unroll
        for (int r = 0; r < 4; ++r) {
          const int rowl = wr + i * 16 + quad * 4 + r;
          float val = acc[i][j][r] + bias;
          float c = fminf(fmaxf(val, -10.f), 10.f);
          ao[(size_t)(bm0 + rowl) * DIMM + nc] = 1.f / (1.f + expf(-c));
        }
    }
  } else {
    // bf16 paths: LDS transpose -> dwordx4 stores.
    ushort_t* outp = (p_id == 0) ? qo : (p_id == 1) ? ko : (p_id == 2) ? vo : bo;
    const float scl = (p_id <= 1) ? 0.125f : 1.f;
    ushort_t* T = (ushort_t*)smem;      // [64][136] bf16 = 17 KiB (tiles dead)
    const int halfb = (wr == 64) ? 32 : 0;
#pragma unroll
    for (int pass = 0; pass < 2; ++pass) {
      __syncthreads();                  // T free (prev reads done)
#pragma unroll
      for (int ii = 0; ii < 2; ++ii) {
        const int i = pass * 2 + ii;
#pragma unroll
        for (int j = 0; j < 4; ++j) {
          const int col = wc + j * 16 + lr;
          const float bias = bias_st[bn0 + col];
#pragma unroll
          for (int r = 0; r < 4; ++r) {
            float val = acc[i][j][r] + bias;
            float ov;
            if (p_id == 3) ov = (val > 20.f) ? val : log1pf(expf(val));
            else ov = val * scl;
            T[(halfb + ii * 16 + quad * 4 + r) * 136 + col] = f2bf(ov);
          }
        }
      }
      __syncthreads();
      // 64 rows x 128 cols out: thread -> row tid>>2, 64B col chunk
      const int trw = tid >> 2;
      const int cch = (tid & 3) * 32;
      const int growl = pass * 32 + (trw & 31) + (trw >> 5) * 64;
      ushort_t* dst = outp + (size_t)(bm0 + growl) * DIMM + ncol0 + cch;
      const ushort_t* src = T + trw * 136 + cch;
#pragma unroll
      for (int u = 0; u < 4; ++u)
        *(uint4*)(dst + u * 8) = *(const uint4*)(src + u * 8);
    }
  }
}

#undef STAGEP
#undef BARR
#undef VMC0

// ---------------------------------------------------------------------------
// Kernel 3: per-(b,n,h) stats.
// ---------------------------------------------------------------------------
__global__ __launch_bounds__(128) void k_stats(
    const float* __restrict__ alpha, const ushort_t* __restrict__ betaw,
    float* __restrict__ mArr, float* __restrict__ bmean, float* __restrict__ asum) {
  const int bnh = blockIdx.x;
  const int h = bnh & 15, n = (bnh >> 4) & 31, b = bnh >> 9;
  const int c = threadIdx.x;
  const size_t bt = (size_t)b * TLEN + n * CHUNKC + c;

  const float4* ap = (const float4*)(alpha + bt * DIMM + h * HEADD);
  float ls = 0.f;
#pragma unroll
  for (int w = 0; w < 16; ++w) {
    float4 a = ap[w];
    ls += logf(a.x) + logf(a.y) + logf(a.z) + logf(a.w);
  }
  const uint4* bp = (const uint4*)(betaw + bt * DIMM + h * HEADD);
  float bs = 0.f;
#pragma unroll
  for (int w = 0; w < 8; ++w) {
    uint4 u = bp[w];
    bs += blo(u.x) + bhi(u.x) + blo(u.y) + bhi(u.y) + blo(u.z) + bhi(u.z) + blo(u.w) + bhi(u.w);
  }
  float la = ls * (1.f / 64.f);

  __shared__ float s[128];
  s[c] = la;
  __syncthreads();
  for (int off = 1; off < 128; off <<= 1) {
    float t = (c >= off) ? s[c - off] : 0.f;
    __syncthreads();
    s[c] += t;
    __syncthreads();
  }
  float m = s[c];
  const size_t o = (size_t)bnh * CHUNKC + c;
  mArr[o] = m;
  bmean[o] = bs * (1.f / 64.f);
  if (c == 127) asum[bnh] = expf(m);
}

// ---------------------------------------------------------------------------
// Kernel 4: delta[b,n,h,kd,vd] = sum_c k[c,kd]*v[c,vd]*bmean[c]
// ---------------------------------------------------------------------------
__global__ __launch_bounds__(256) void k_delta(
    const ushort_t* __restrict__ kw, const ushort_t* __restrict__ vw,
    const float* __restrict__ bmean, float* __restrict__ delta) {
  __shared__ ushort_t kc[8192];
  __shared__ ushort_t vc[8192];
  __shared__ float bm[128];
  const int bnh = blockIdx.x;
  const int h = bnh & 15, n = (bnh >> 4) & 31, b = bnh >> 9;
  const int tid = threadIdx.x;
  const size_t bt0 = (size_t)b * TLEN + n * CHUNKC;

#pragma unroll
  for (int it = 0; it < 4; ++it) {
    int u = tid + it * 256;
    int row = u >> 3, col = (u & 7) * 8;
    size_t go = (bt0 + row) * DIMM + h * HEADD + col;
    ((uint4*)kc)[u] = *(const uint4*)(kw + go);
    ((uint4*)vc)[u] = *(const uint4*)(vw + go);
  }
  if (tid < 128) bm[tid] = bmean[(size_t)bnh * CHUNKC + tid];
  __syncthreads();

  const int kd = tid >> 2, v0 = (tid & 3) * 16;
  float acc[16];
#pragma unroll
  for (int l = 0; l < 16; ++l) acc[l] = 0.f;

#pragma unroll 4
  for (int c = 0; c < 128; ++c) {
    float kb = bf2f(kc[c * 64 + kd]) * bm[c];
    const uint4* vr = (const uint4*)(vc + c * 64 + v0);
    uint4 u0 = vr[0], u1 = vr[1];
    acc[0] += kb * blo(u0.x);  acc[1] += kb * bhi(u0.x);
    acc[2] += kb * blo(u0.y);  acc[3] += kb * bhi(u0.y);
    acc[4] += kb * blo(u0.z);  acc[5] += kb * bhi(u0.z);
    acc[6] += kb * blo(u0.w);  acc[7] += kb * bhi(u0.w);
    acc[8] += kb * blo(u1.x);  acc[9] += kb * bhi(u1.x);
    acc[10] += kb * blo(u1.y); acc[11] += kb * bhi(u1.y);
    acc[12] += kb * blo(u1.z); acc[13] += kb * bhi(u1.z);
    acc[14] += kb * blo(u1.w); acc[15] += kb * bhi(u1.w);
  }
  float* dst = delta + (size_t)bnh * 4096 + kd * 64 + v0;
#pragma unroll
  for (int l4 = 0; l4 < 4; ++l4)
    ((float4*)dst)[l4] = make_float4(acc[l4 * 4], acc[l4 * 4 + 1], acc[l4 * 4 + 2], acc[l4 * 4 + 3]);
}

// ---------------------------------------------------------------------------
// Kernel 5: scan over chunks. 1024 blocks: (b,h,group of 256 state elems).
// E_{n+1} = E_n * asum_n + delta_n. Entry states -> Earr; final -> state_out.
// ---------------------------------------------------------------------------
__global__ __launch_bounds__(256) void k_scan(
    const float* __restrict__ delta, const float* __restrict__ asum,
    float* __restrict__ Earr, float* __restrict__ state_out) {
  const int bh = blockIdx.x >> 4;        // b*16+h
  const int g = blockIdx.x & 15;
  const int b = bh >> 4, h = bh & 15;
  const int elem = g * 256 + threadIdx.x;
  float e = 0.f;
  for (int n = 0; n < 32; ++n) {
    const size_t o = (((size_t)b * 32 + n) * 16 + h) * 4096 + elem;
    const float a = asum[((size_t)b * 32 + n) * 16 + h];
    Earr[o] = e;
    e = e * a + delta[o];
  }
  state_out[(size_t)bh * 4096 + elem] = e;
}

// ---------------------------------------------------------------------------
// Kernel 6 (MFMA rewrite): per (b,n,h) block, 256 threads = 4 waves.
// GEMM1: S = q k^T (128x128x64), decay+mask in C-layout, P staged per-wave
// in LDS (A-layout round trip). GEMM2: y = P_ext @ Vb_ext, K=192 where
// columns 128..191 carry the inter-chunk memory term: P[i][128+kd] =
// q[i][kd]*exp(m_i), Vb_ext[128+kd][vd] = E[kd][vd].
// q/k fragments are read directly from global (L1-served, 4-wave reuse).
// ---------------------------------------------------------------------------
__global__ __launch_bounds__(256) void k_y(
    const ushort_t* __restrict__ qw, const ushort_t* __restrict__ kw,
    const ushort_t* __restrict__ vw, const ushort_t* __restrict__ betaw,
    const float* __restrict__ mArr, const float* __restrict__ Earr,
    float* __restrict__ yout) {
  // VbT[vd][j'] : j' in [0,192): 0..127 = (v*beta)^T, 128..191 = E^T column kd
  __shared__ __align__(16) ushort_t vbt[64][200];   // 25600 B (stride 400B: 2-way max)
  __shared__ __align__(16) ushort_t pst[4][32][40]; // 10240 B per-wave P staging
  __shared__ float ms[128];                         // 512 B
  const int bnh = blockIdx.x;
  const int h = bnh & 15, n = (bnh >> 4) & 31, b = bnh >> 9;
  const int tid = threadIdx.x;
  const int lane = tid & 63;
  const int wv = tid >> 6;
  const int quad = lane >> 4, lr = lane & 15;
  const int i0 = wv * 32;
  const size_t bt0 = (size_t)b * TLEN + n * CHUNKC;
  const size_t hoff = (size_t)h * HEADD;

  // ---- Phase A: stage VbT (v*beta transposed) + E^T + m ----
#pragma unroll
  for (int it = 0; it < 4; ++it) {
    int u = tid + it * 256;          // 0..1023
    int j = u & 127, vd0 = (u >> 7) * 8;
    size_t go = (bt0 + j) * DIMM + hoff + vd0;
    uint4 vv = *(const uint4*)(vw + go);
    uint4 bb2 = *(const uint4*)(betaw + go);
    vbt[vd0 + 0][j] = f2bf(blo(vv.x) * blo(bb2.x));
    vbt[vd0 + 1][j] = f2bf(bhi(vv.x) * bhi(bb2.x));
    vbt[vd0 + 2][j] = f2bf(blo(vv.y) * blo(bb2.y));
    vbt[vd0 + 3][j] = f2bf(bhi(vv.y) * bhi(bb2.y));
    vbt[vd0 + 4][j] = f2bf(blo(vv.z) * blo(bb2.z));
    vbt[vd0 + 5][j] = f2bf(bhi(vv.z) * bhi(bb2.z));
    vbt[vd0 + 6][j] = f2bf(blo(vv.w) * blo(bb2.w));
    vbt[vd0 + 7][j] = f2bf(bhi(vv.w) * bhi(bb2.w));
  }
  const float4* Eg = (const float4*)(Earr + (size_t)bnh * 4096);
#pragma unroll
  for (int it = 0; it < 4; ++it) {
    int u = tid + it * 256;          // 0..1023 float4 units
    int kd = u >> 4, vd0 = (u & 15) * 4;
    float4 ev = Eg[u];
    vbt[vd0 + 0][128 + kd] = f2bf(ev.x);
    vbt[vd0 + 1][128 + kd] = f2bf(ev.y);
    vbt[vd0 + 2][128 + kd] = f2bf(ev.z);
    vbt[vd0 + 3][128 + kd] = f2bf(ev.w);
  }
  if (tid < 128) ms[tid] = mArr[(size_t)bnh * CHUNKC + tid];
  __syncthreads();

  // ---- per-lane q A-fragments (from global) + row decay consts ----
  short8 qa[2][2];
#pragma unroll
  for (int it = 0; it < 2; ++it) {
    const ushort_t* qg = qw + (bt0 + i0 + it * 16 + lr) * DIMM + hoff + quad * 8;
    qa[it][0] = *(const short8*)(qg);
    qa[it][1] = *(const short8*)(qg + 32);
  }
  float mi[2][4];
#pragma unroll
  for (int it = 0; it < 2; ++it)
#pragma unroll
    for (int r = 0; r < 4; ++r) mi[it][r] = ms[i0 + it * 16 + quad * 4 + r];

  f32x4 zero = {0.f, 0.f, 0.f, 0.f};
  f32x4 acc2[2][4];
#pragma unroll
  for (int it = 0; it < 2; ++it)
#pragma unroll
    for (int nt = 0; nt < 4; ++nt) acc2[it][nt] = zero;

  // ---- attention steps: 4 x (32 j-columns) ----
  for (int js = 0; js < 4; ++js) {
    const int j0 = js * 32;
#pragma unroll
    for (int jsub = 0; jsub < 2; ++jsub) {
      const int j0s = j0 + jsub * 16;
      const ushort_t* kg = kw + (bt0 + j0s + lr) * DIMM + hoff + quad * 8;
      short8 kb0 = *(const short8*)(kg);
      short8 kb1 = *(const short8*)(kg + 32);
      const float mj = ms[j0s + lr];
#pragma unroll
      for (int it = 0; it < 2; ++it) {
        f32x4 s = __builtin_amdgcn_mfma_f32_16x16x32_bf16(qa[it][0], kb0, zero, 0, 0, 0);
        s = __builtin_amdgcn_mfma_f32_16x16x32_bf16(qa[it][1], kb1, s, 0, 0, 0);
#pragma unroll
        for (int r = 0; r < 4; ++r) {
          const int ig = i0 + it * 16 + quad * 4 + r;
          const int jg = j0s + lr;
          float w = (jg > ig) ? 0.f : s[r] * __expf(mi[it][r] - mj);
          pst[wv][it * 16 + quad * 4 + r][jsub * 16 + lr] = f2bf(w);
        }
      }
    }
    // GEMM2 accumulate this 32-wide K slab (LDS ops in-order within wave)
#pragma unroll
    for (int it = 0; it < 2; ++it) {
      short8 pa = *(const short8*)&pst[wv][it * 16 + lr][quad * 8];
#pragma unroll
      for (int nt = 0; nt < 4; ++nt) {
        short8 vb = *(const short8*)&vbt[nt * 16 + lr][j0 + quad * 8];
        acc2[it][nt] = __builtin_amdgcn_mfma_f32_16x16x32_bf16(pa, vb, acc2[it][nt], 0, 0, 0);
      }
    }
  }

  // ---- memory-term steps: 2 x (32 kd-columns): P = q*exp(m_i), V = E ----
#pragma unroll
  for (int es = 0; es < 2; ++es) {
    const int kd0 = es * 32;
    {
      const int row = lane >> 1;
      const int col0 = (lane & 1) * 16;
      const float ex = __expf(ms[i0 + row]);
      const ushort_t* qg = qw + (bt0 + i0 + row) * DIMM + hoff + kd0 + col0;
      uint4 u0 = *(const uint4*)(qg);
      uint4 u1 = *(const uint4*)(qg + 8);
      uint4 w0, w1;
      w0.x = pack2(blo(u0.x) * ex, bhi(u0.x) * ex);
      w0.y = pack2(blo(u0.y) * ex, bhi(u0.y) * ex);
      w0.z = pack2(blo(u0.z) * ex, bhi(u0.z) * ex);
      w0.w = pack2(blo(u0.w) * ex, bhi(u0.w) * ex);
      w1.x = pack2(blo(u1.x) * ex, bhi(u1.x) * ex);
      w1.y = pack2(blo(u1.y) * ex, bhi(u1.y) * ex);
      w1.z = pack2(blo(u1.z) * ex, bhi(u1.z) * ex);
      w1.w = pack2(blo(u1.w) * ex, bhi(u1.w) * ex);
      *(uint4*)&pst[wv][row][col0] = w0;
      *(uint4*)&pst[wv][row][col0 + 8] = w1;
    }
#pragma unroll
    for (int it = 0; it < 2; ++it) {
      short8 pa = *(const short8*)&pst[wv][it * 16 + lr][quad * 8];
#pragma unroll
      for (int nt = 0; nt < 4; ++nt) {
        short8 vb = *(const short8*)&vbt[nt * 16 + lr][128 + kd0 + quad * 8];
        acc2[it][nt] = __builtin_amdgcn_mfma_f32_16x16x32_bf16(pa, vb, acc2[it][nt], 0, 0, 0);
      }
    }
  }

  // ---- epilogue: C-layout scatter to y (fp32) ----
#pragma unroll
  for (int it = 0; it < 2; ++it) {
#pragma unroll
    for (int nt = 0; nt < 4; ++nt) {
      f32x4 a = acc2[it][nt];
#pragma unroll
      for (int r = 0; r < 4; ++r) {
        const int ig = i0 + it * 16 + quad * 4 + r;
        yout[(bt0 + ig) * DIMM + hoff + nt * 16 + lr] = a[r];
      }
    }
  }
}

// ---------------------------------------------------------------------------
extern "C" void kernel_launch(void* const* d_in, const int* in_sizes, int n_in,
                              void* d_out, int out_size, void* d_ws, size_t ws_size,
                              hipStream_t stream) {
  const float* x  = (const float*)d_in[0];
  const float* Wq = (const float*)d_in[1];
  const float* bq = (const float*)d_in[2];
  const float* Wk = (const float*)d_in[3];
  const float* bk = (const float*)d_in[4];
  const float* Wv = (const float*)d_in[5];
  const float* bv = (const float*)d_in[6];
  const float* Wb = (const float*)d_in[7];
  const float* bb = (const float*)d_in[8];
  const float* Wa = (const float*)d_in[9];
  const float* ba = (const float*)d_in[10];

  char* ws = (char*)d_ws;
  ushort_t* xb   = (ushort_t*)(ws + 0);           // 33554432 B
  ushort_t* wbm  = (ushort_t*)(ws + 33554432);    // 10485760 B
  float* bias_st = (float*)(ws + 44040192);       // 20480 B
  ushort_t* qw   = (ushort_t*)(ws + 44060672);    // 33554432 B
  ushort_t* kw   = (ushort_t*)(ws + 77615104);    // 33554432 B
  ushort_t* vw   = (ushort_t*)(ws + 111169536);   // 33554432 B
  ushort_t* bw   = (ushort_t*)(ws + 144723968);   // 33554432 B
  float* mArr    = (float*)(ws + 178278400);      // 1048576 B
  float* bmean   = (float*)(ws + 179326976);      // 1048576 B
  float* asum    = (float*)(ws + 180375552);      // 8192 B
  float* delta   = (float*)(ws + 180383744);      // 33554432 B
  float* Earr    = (float*)(ws + 213938176);      // 33554432 B  (total 247492608)

  float* yout = (float*)d_out;
  float* state_out = yout + (size_t)BT * DIMM;                 // + 16777216
  float* aout = state_out + (size_t)NBATCH * NHEAD * 64 * 64;  // + 262144

  k_cast<<<dim3(4096), dim3(256), 0, stream>>>(x, Wq, Wk, Wv, Wb, Wa,
                                               bq, bk, bv, bb, ba, xb, wbm, bias_st);
  k_proj<<<dim3(40, 128), dim3(256), 0, stream>>>(xb, wbm, bias_st, qw, kw, vw, bw, aout);
  k_stats<<<dim3(2048), dim3(128), 0, stream>>>(aout, bw, mArr, bmean, asum);
  k_delta<<<dim3(2048), dim3(256), 0, stream>>>(kw, vw, bmean, delta);
  k_scan<<<dim3(1024), dim3(256), 0, stream>>>(delta, asum, Earr, state_out);
  k_y<<<dim3(2048), dim3(256), 0, stream>>>(qw, kw, vw, bw, mArr, Earr, yout);
}